// Round 3
// baseline (9027.661 us; speedup 1.0000x reference)
//
#include <hip/hip_runtime.h>
#include <hip/hip_bf16.h>

#define N_NODES 50000
#define N_EDGES 800000
#define H 64
#define ED 32
#define LAYERS 3
#define NGRAPH 256
#define OUTD 32
#define SCALE 0.125f

// monotone float->unsigned key: order-preserving for all floats (incl -0.0)
__device__ __forceinline__ unsigned f2ord(float f) {
    unsigned b = __float_as_uint(f);
    return (b & 0x80000000u) ? ~b : (b | 0x80000000u);
}
__device__ __forceinline__ float ord2f(unsigned k) {
    unsigned b = (k & 0x80000000u) ? (k & 0x7FFFFFFFu) : ~k;
    return __uint_as_float(b);
}

// ---------------- init: h = node_emb[x] ----------------
__global__ void k_init_h(const int* __restrict__ x, const float* __restrict__ node_emb,
                         float* __restrict__ h) {
    int i = blockIdx.x * blockDim.x + threadIdx.x;
    if (i >= N_NODES * H) return;
    int n = i >> 6, c = i & 63;
    h[i] = node_emb[x[n] * H + c];
}

// ---------------- te[l][cat][c] = sum_d edge_emb[cat][d] * We[l][d][c] ----------------
__global__ void k_te(const float* __restrict__ edge_emb, const float* __restrict__ We,
                     float* __restrict__ te) {
    int i = blockIdx.x * blockDim.x + threadIdx.x;
    if (i >= LAYERS * 10 * H) return;
    int c = i & 63;
    int cat = (i >> 6) % 10;
    int l = i / (10 * H);
    float acc = 0.f;
    for (int d = 0; d < ED; d++)
        acc += edge_emb[cat * ED + d] * We[((size_t)l * ED + d) * H + c];
    te[i] = acc;
}

// ---------------- fused node GEMM: q,k,v,skip = h @ W* + b* ----------------
// 64 nodes per block; weights cached in LDS in two 32-column halves (4*64*32*4B = 32KB)
// + all 64 h-rows (padded, ~16.6KB). Total LDS ~49KB.
__global__ __launch_bounds__(256) void k_node_gemm(
    const float* __restrict__ h,
    const float* __restrict__ Wq, const float* __restrict__ Wk,
    const float* __restrict__ Wv, const float* __restrict__ Wsk,
    const float* __restrict__ bq, const float* __restrict__ bk,
    const float* __restrict__ bv, const float* __restrict__ bsk,
    float* __restrict__ q, float* __restrict__ k, float* __restrict__ v, float* __restrict__ s)
{
    __shared__ float wts[4][64][32];
    __shared__ float hr[64][65];
    int tid = threadIdx.x;
    int base = blockIdx.x * 64;
    // load 64 h rows (coalesced)
    for (int i = tid; i < 64 * 64; i += 256) {
        int r = i >> 6, c = i & 63;
        int n = base + r;
        hr[r][c] = (n < N_NODES) ? h[(size_t)n * H + c] : 0.f;
    }
    for (int ch = 0; ch < 2; ch++) {
        __syncthreads();
        for (int i = tid; i < 64 * 32; i += 256) {
            int r = i >> 5, c = i & 31;
            int off = r * H + ch * 32 + c;
            wts[0][r][c] = Wq[off];
            wts[1][r][c] = Wk[off];
            wts[2][r][c] = Wv[off];
            wts[3][r][c] = Wsk[off];
        }
        __syncthreads();
        int c = tid & 31, ln = tid >> 5;   // 8 nodes in flight
        float b0 = bq[ch * 32 + c], b1 = bk[ch * 32 + c];
        float b2 = bv[ch * 32 + c], b3 = bsk[ch * 32 + c];
        for (int r0 = 0; r0 < 64; r0 += 8) {
            int r = r0 + ln;
            int n = base + r;
            if (n < N_NODES) {
                float a0 = 0.f, a1 = 0.f, a2 = 0.f, a3 = 0.f;
                #pragma unroll
                for (int kk = 0; kk < 64; kk++) {
                    float hv = hr[r][kk];
                    a0 += hv * wts[0][kk][c];
                    a1 += hv * wts[1][kk][c];
                    a2 += hv * wts[2][kk][c];
                    a3 += hv * wts[3][kk][c];
                }
                size_t o = (size_t)n * H + ch * 32 + c;
                q[o] = a0 + b0; k[o] = a1 + b1; v[o] = a2 + b2; s[o] = a3 + b3;
            }
        }
    }
}

// ---------------- edge pass 1: alpha + per-dst max ----------------
__global__ __launch_bounds__(256) void k_edge1(
    const int* __restrict__ ei, const int* __restrict__ ea,
    const float* __restrict__ q, const float* __restrict__ k,
    const float* __restrict__ te, float* __restrict__ alpha, unsigned* __restrict__ mx)
{
    int e = blockIdx.x * blockDim.x + threadIdx.x;
    if (e >= N_EDGES) return;
    int src = ei[e], dst = ei[N_EDGES + e];
    int cat = ea[e];
    const float4* qp = (const float4*)(q + (size_t)dst * H);
    const float4* kp = (const float4*)(k + (size_t)src * H);
    const float4* tp = (const float4*)(te + (size_t)cat * H);
    float acc = 0.f;
    #pragma unroll
    for (int i = 0; i < 16; i++) {
        float4 a = qp[i], b = kp[i], t = tp[i];
        acc += a.x * (b.x + t.x) + a.y * (b.y + t.y) + a.z * (b.z + t.z) + a.w * (b.w + t.w);
    }
    acc *= SCALE;
    alpha[e] = acc;
    atomicMax(&mx[dst], f2ord(acc));
}

// ---------------- edge pass 2: weighted message accumulation ----------------
__global__ __launch_bounds__(256) void k_edge2(
    const int* __restrict__ ei, const int* __restrict__ ea,
    const float* __restrict__ v, const float* __restrict__ te,
    const float* __restrict__ alpha, const unsigned* __restrict__ mx,
    float* __restrict__ agg, float* __restrict__ denom)
{
    int e = blockIdx.x * blockDim.x + threadIdx.x;
    if (e >= N_EDGES) return;
    int src = ei[e], dst = ei[N_EDGES + e];
    int cat = ea[e];
    float m = ord2f(mx[dst]);
    float w = __expf(alpha[e] - m);
    atomicAdd(&denom[dst], w);
    const float* vp = v + (size_t)src * H;
    const float* tp = te + (size_t)cat * H;
    float* ap = agg + (size_t)dst * H;
    #pragma unroll 8
    for (int i = 0; i < H; i++) atomicAdd(&ap[i], w * (vp[i] + tp[i]));
}

// ---------------- node update: h = relu(agg/denom + skip) ----------------
__global__ void k_update(const float* __restrict__ agg, const float* __restrict__ denom,
                         const float* __restrict__ s, float* __restrict__ h)
{
    int i = blockIdx.x * blockDim.x + threadIdx.x;
    if (i >= N_NODES * H) return;
    int n = i >> 6;
    float d = denom[n];
    float a = (d > 0.f) ? agg[i] / d : 0.f;
    float r = a + s[i];
    h[i] = r > 0.f ? r : 0.f;
}

// ---------------- readout gate: gate = h @ gate_W + b; per-graph max ----------------
__global__ void k_gate(const float* __restrict__ h, const float* __restrict__ gW,
                       const float* __restrict__ gb, const int* __restrict__ batch,
                       float* __restrict__ gate, unsigned* __restrict__ gmax)
{
    int n = blockIdx.x * blockDim.x + threadIdx.x;
    if (n >= N_NODES) return;
    float acc = gb[0];
    const float* hp = h + (size_t)n * H;
    #pragma unroll
    for (int i = 0; i < H; i++) acc += hp[i] * gW[i];
    gate[n] = acc;
    atomicMax(&gmax[batch[n]], f2ord(acc));
}

// ---------------- readout accumulation: outacc[g][o] += w * (h@out_W + b)[o] ----------------
__global__ __launch_bounds__(256) void k_readout(
    const float* __restrict__ h, const float* __restrict__ oW,
    const float* __restrict__ ob, const int* __restrict__ batch,
    const float* __restrict__ gate, const unsigned* __restrict__ gmax,
    float* __restrict__ gden, float* __restrict__ outacc)
{
    __shared__ float w[H * OUTD];
    for (int i = threadIdx.x; i < H * OUTD; i += 256) w[i] = oW[i];
    __syncthreads();
    int t = blockIdx.x * blockDim.x + threadIdx.x;
    int n = t >> 5, o = t & 31;
    if (n >= N_NODES) return;
    int b = batch[n];
    float wt = __expf(gate[n] - ord2f(gmax[b]));
    if (o == 0) atomicAdd(&gden[b], wt);
    const float* hp = h + (size_t)n * H;
    float acc = ob[o];
    #pragma unroll
    for (int i = 0; i < H; i++) acc += hp[i] * w[i * OUTD + o];
    atomicAdd(&outacc[b * OUTD + o], wt * acc);
}

// ---------------- final: out = outacc / gden (float32 output) ----------------
__global__ void k_final(const float* __restrict__ outacc, const float* __restrict__ gden,
                        float* __restrict__ out)
{
    int i = blockIdx.x * blockDim.x + threadIdx.x;
    if (i >= NGRAPH * OUTD) return;
    int g = i >> 5;
    float d = gden[g];
    out[i] = d > 0.f ? outacc[i] / d : 0.f;
}

extern "C" void kernel_launch(void* const* d_in, const int* in_sizes, int n_in,
                              void* d_out, int out_size, void* d_ws, size_t ws_size,
                              hipStream_t stream)
{
    const int* x        = (const int*)d_in[0];
    const int* ei       = (const int*)d_in[1];
    const int* ea       = (const int*)d_in[2];
    const int* batch    = (const int*)d_in[3];
    const float* node_emb = (const float*)d_in[4];
    const float* edge_emb = (const float*)d_in[5];
    const float* Wq    = (const float*)d_in[6];
    const float* Wk    = (const float*)d_in[7];
    const float* Wv    = (const float*)d_in[8];
    const float* We    = (const float*)d_in[9];
    const float* Wskip = (const float*)d_in[10];
    const float* bq    = (const float*)d_in[11];
    const float* bk    = (const float*)d_in[12];
    const float* bv    = (const float*)d_in[13];
    const float* bskip = (const float*)d_in[14];
    const float* gate_W = (const float*)d_in[15];
    const float* gate_b = (const float*)d_in[16];
    const float* out_W  = (const float*)d_in[17];
    const float* out_b  = (const float*)d_in[18];
    float* out = (float*)d_out;   // reference output dtype is float32

    const size_t NH = (size_t)N_NODES * H;
    float* ws   = (float*)d_ws;
    float* h    = ws;
    float* q    = h + NH;
    float* k    = q + NH;
    float* v    = k + NH;
    float* s    = v + NH;
    float* agg  = s + NH;            // agg, denom, mx contiguous -> one memset
    float* denom = agg + NH;
    unsigned* mx = (unsigned*)(denom + N_NODES);
    float* alpha = (float*)(mx + N_NODES);
    float* gate  = alpha + N_EDGES;
    float* te    = gate + N_NODES;
    unsigned* gmax = (unsigned*)(te + LAYERS * 10 * H);  // gmax, gden, outacc contiguous
    float* gden   = (float*)(gmax + NGRAPH);
    float* outacc = gden + NGRAPH;

    k_init_h<<<(N_NODES * H + 255) / 256, 256, 0, stream>>>(x, node_emb, h);
    k_te<<<(LAYERS * 10 * H + 255) / 256, 256, 0, stream>>>(edge_emb, We, te);

    for (int l = 0; l < LAYERS; l++) {
        // zero agg + denom + mx (mx key-space: 0 == "below any real float" sentinel)
        hipMemsetAsync(agg, 0, (NH + 2 * (size_t)N_NODES) * sizeof(float), stream);
        k_node_gemm<<<(N_NODES + 63) / 64, 256, 0, stream>>>(
            h,
            Wq + (size_t)l * H * H, Wk + (size_t)l * H * H,
            Wv + (size_t)l * H * H, Wskip + (size_t)l * H * H,
            bq + (size_t)l * H, bk + (size_t)l * H, bv + (size_t)l * H, bskip + (size_t)l * H,
            q, k, v, s);
        k_edge1<<<(N_EDGES + 255) / 256, 256, 0, stream>>>(ei, ea, q, k, te + (size_t)l * 10 * H, alpha, mx);
        k_edge2<<<(N_EDGES + 255) / 256, 256, 0, stream>>>(ei, ea, v, te + (size_t)l * 10 * H, alpha, mx, agg, denom);
        k_update<<<(N_NODES * H + 255) / 256, 256, 0, stream>>>(agg, denom, s, h);
    }

    // zero gmax + gden + outacc
    hipMemsetAsync(gmax, 0, (2 * (size_t)NGRAPH + (size_t)NGRAPH * OUTD) * sizeof(float), stream);
    k_gate<<<(N_NODES + 255) / 256, 256, 0, stream>>>(h, gate_W, gate_b, batch, gate, gmax);
    k_readout<<<(N_NODES * OUTD + 255) / 256, 256, 0, stream>>>(h, out_W, out_b, batch, gate, gmax, gden, outacc);
    k_final<<<(NGRAPH * OUTD + 255) / 256, 256, 0, stream>>>(outacc, gden, out);
}

// Round 4
// 1079.850 us; speedup vs baseline: 8.3601x; 8.3601x over previous
//
#include <hip/hip_runtime.h>
#include <hip/hip_bf16.h>

#define N_NODES 50000
#define N_EDGES 800000
#define H 64
#define ED 32
#define LAYERS 3
#define NGRAPH 256
#define OUTD 32
#define SCALE 0.125f

// monotone float->unsigned key: order-preserving for all floats (incl -0.0)
__device__ __forceinline__ unsigned f2ord(float f) {
    unsigned b = __float_as_uint(f);
    return (b & 0x80000000u) ? ~b : (b | 0x80000000u);
}
__device__ __forceinline__ float ord2f(unsigned k) {
    unsigned b = (k & 0x80000000u) ? (k & 0x7FFFFFFFu) : ~k;
    return __uint_as_float(b);
}

// ---------------- init: h = node_emb[x] ----------------
__global__ void k_init_h(const int* __restrict__ x, const float* __restrict__ node_emb,
                         float* __restrict__ h) {
    int i = blockIdx.x * blockDim.x + threadIdx.x;
    if (i >= N_NODES * H) return;
    int n = i >> 6, c = i & 63;
    h[i] = node_emb[x[n] * H + c];
}

// ---------------- te[l][cat][c] = sum_d edge_emb[cat][d] * We[l][d][c] ----------------
__global__ void k_te(const float* __restrict__ edge_emb, const float* __restrict__ We,
                     float* __restrict__ te) {
    int i = blockIdx.x * blockDim.x + threadIdx.x;
    if (i >= LAYERS * 10 * H) return;
    int c = i & 63;
    int cat = (i >> 6) % 10;
    int l = i / (10 * H);
    float acc = 0.f;
    for (int d = 0; d < ED; d++)
        acc += edge_emb[cat * ED + d] * We[((size_t)l * ED + d) * H + c];
    te[i] = acc;
}

// ---------------- CSR build: histogram / scan / scatter ----------------
__global__ void k_hist(const int* __restrict__ ei, int* __restrict__ deg) {
    int e = blockIdx.x * blockDim.x + threadIdx.x;
    if (e >= N_EDGES) return;
    atomicAdd(&deg[ei[N_EDGES + e]], 1);
}

// single-block exclusive scan over deg[N_NODES] -> row_start, cursor
__global__ __launch_bounds__(1024) void k_scan(const int* __restrict__ deg,
                                               int* __restrict__ row_start,
                                               int* __restrict__ cursor) {
    __shared__ int part[1024];
    int t = threadIdx.x;
    const int CH = (N_NODES + 1023) / 1024;   // 49
    int lo = t * CH, hi = min(lo + CH, N_NODES);
    int sum = 0;
    for (int i = lo; i < hi; i++) sum += deg[i];
    part[t] = sum;
    __syncthreads();
    for (int off = 1; off < 1024; off <<= 1) {
        int add = (t >= off) ? part[t - off] : 0;
        __syncthreads();
        part[t] += add;
        __syncthreads();
    }
    int pre = (t == 0) ? 0 : part[t - 1];
    for (int i = lo; i < hi; i++) {
        row_start[i] = pre;
        cursor[i] = pre;
        pre += deg[i];
    }
}

// scatter edges into dst-sorted order; pack src (16b) | cat (<<16)
__global__ void k_scatter(const int* __restrict__ ei, const int* __restrict__ ea,
                          int* __restrict__ cursor, int* __restrict__ packed) {
    int e = blockIdx.x * blockDim.x + threadIdx.x;
    if (e >= N_EDGES) return;
    int src = ei[e], dst = ei[N_EDGES + e], cat = ea[e];
    int pos = atomicAdd(&cursor[dst], 1);
    packed[pos] = src | (cat << 16);
}

// ---------------- fused node GEMM: q,k,v,skip = h @ W* + b* ----------------
__global__ __launch_bounds__(256) void k_node_gemm(
    const float* __restrict__ h,
    const float* __restrict__ Wq, const float* __restrict__ Wk,
    const float* __restrict__ Wv, const float* __restrict__ Wsk,
    const float* __restrict__ bq, const float* __restrict__ bk,
    const float* __restrict__ bv, const float* __restrict__ bsk,
    float* __restrict__ q, float* __restrict__ k, float* __restrict__ v, float* __restrict__ s)
{
    __shared__ float wts[4][64][32];
    __shared__ float hr[64][65];
    int tid = threadIdx.x;
    int base = blockIdx.x * 64;
    for (int i = tid; i < 64 * 64; i += 256) {
        int r = i >> 6, c = i & 63;
        int n = base + r;
        hr[r][c] = (n < N_NODES) ? h[(size_t)n * H + c] : 0.f;
    }
    for (int ch = 0; ch < 2; ch++) {
        __syncthreads();
        for (int i = tid; i < 64 * 32; i += 256) {
            int r = i >> 5, c = i & 31;
            int off = r * H + ch * 32 + c;
            wts[0][r][c] = Wq[off];
            wts[1][r][c] = Wk[off];
            wts[2][r][c] = Wv[off];
            wts[3][r][c] = Wsk[off];
        }
        __syncthreads();
        int c = tid & 31, ln = tid >> 5;
        float b0 = bq[ch * 32 + c], b1 = bk[ch * 32 + c];
        float b2 = bv[ch * 32 + c], b3 = bsk[ch * 32 + c];
        for (int r0 = 0; r0 < 64; r0 += 8) {
            int r = r0 + ln;
            int n = base + r;
            if (n < N_NODES) {
                float a0 = 0.f, a1 = 0.f, a2 = 0.f, a3 = 0.f;
                #pragma unroll
                for (int kk = 0; kk < 64; kk++) {
                    float hv = hr[r][kk];
                    a0 += hv * wts[0][kk][c];
                    a1 += hv * wts[1][kk][c];
                    a2 += hv * wts[2][kk][c];
                    a3 += hv * wts[3][kk][c];
                }
                size_t o = (size_t)n * H + ch * 32 + c;
                q[o] = a0 + b0; k[o] = a1 + b1; v[o] = a2 + b2; s[o] = a3 + b3;
            }
        }
    }
}

// ---------------- fused gather: alpha + online softmax + agg + skip + relu ----------------
// one wave per dst node; lane = channel
__global__ __launch_bounds__(256) void k_agg(
    const int* __restrict__ row_start, const int* __restrict__ row_end,
    const int* __restrict__ packed,
    const float* __restrict__ q, const float* __restrict__ k,
    const float* __restrict__ v, const float* __restrict__ s,
    const float* __restrict__ te, float* __restrict__ h)
{
    __shared__ float tel[10 * 64];
    for (int i = threadIdx.x; i < 10 * 64; i += 256) tel[i] = te[i];
    __syncthreads();
    int wave = threadIdx.x >> 6;
    int lane = threadIdx.x & 63;
    int dst = blockIdx.x * 4 + wave;
    if (dst >= N_NODES) return;
    int beg = row_start[dst], end = row_end[dst];
    float qv = q[(size_t)dst * H + lane];
    float m = -INFINITY, l = 0.f, acc = 0.f;
    for (int p0 = beg; p0 < end; p0 += 64) {
        int pk = (p0 + lane < end) ? packed[p0 + lane] : 0;
        int cnt = min(64, end - p0);
        for (int i = 0; i < cnt; i++) {
            int pkt = __shfl(pk, i);
            int src = pkt & 0xFFFF;
            int cat = pkt >> 16;
            float t = tel[cat * 64 + lane];
            float kv = k[(size_t)src * H + lane] + t;
            float part = qv * kv;
            #pragma unroll
            for (int d = 1; d < 64; d <<= 1) part += __shfl_xor(part, d);
            float a = part * SCALE;
            float mn = fmaxf(m, a);
            float corr = __expf(m - mn);
            float w = __expf(a - mn);
            float vv = v[(size_t)src * H + lane] + t;
            acc = acc * corr + w * vv;
            l = l * corr + w;
            m = mn;
        }
    }
    float outv = (l > 0.f) ? acc / l : 0.f;
    float r = outv + s[(size_t)dst * H + lane];
    h[(size_t)dst * H + lane] = fmaxf(r, 0.f);
}

// ---------------- readout gate: gate = h @ gate_W + b; per-graph max ----------------
__global__ void k_gate(const float* __restrict__ h, const float* __restrict__ gW,
                       const float* __restrict__ gb, const int* __restrict__ batch,
                       float* __restrict__ gate, unsigned* __restrict__ gmax)
{
    int n = blockIdx.x * blockDim.x + threadIdx.x;
    if (n >= N_NODES) return;
    float acc = gb[0];
    const float* hp = h + (size_t)n * H;
    #pragma unroll
    for (int i = 0; i < H; i++) acc += hp[i] * gW[i];
    gate[n] = acc;
    atomicMax(&gmax[batch[n]], f2ord(acc));
}

// ---------------- readout accumulation ----------------
__global__ __launch_bounds__(256) void k_readout(
    const float* __restrict__ h, const float* __restrict__ oW,
    const float* __restrict__ ob, const int* __restrict__ batch,
    const float* __restrict__ gate, const unsigned* __restrict__ gmax,
    float* __restrict__ gden, float* __restrict__ outacc)
{
    __shared__ float w[H * OUTD];
    for (int i = threadIdx.x; i < H * OUTD; i += 256) w[i] = oW[i];
    __syncthreads();
    int t = blockIdx.x * blockDim.x + threadIdx.x;
    int n = t >> 5, o = t & 31;
    if (n >= N_NODES) return;
    int b = batch[n];
    float wt = __expf(gate[n] - ord2f(gmax[b]));
    if (o == 0) atomicAdd(&gden[b], wt);
    const float* hp = h + (size_t)n * H;
    float acc = ob[o];
    #pragma unroll
    for (int i = 0; i < H; i++) acc += hp[i] * w[i * OUTD + o];
    atomicAdd(&outacc[b * OUTD + o], wt * acc);
}

// ---------------- final ----------------
__global__ void k_final(const float* __restrict__ outacc, const float* __restrict__ gden,
                        float* __restrict__ out)
{
    int i = blockIdx.x * blockDim.x + threadIdx.x;
    if (i >= NGRAPH * OUTD) return;
    int g = i >> 5;
    float d = gden[g];
    out[i] = d > 0.f ? outacc[i] / d : 0.f;
}

extern "C" void kernel_launch(void* const* d_in, const int* in_sizes, int n_in,
                              void* d_out, int out_size, void* d_ws, size_t ws_size,
                              hipStream_t stream)
{
    const int* x        = (const int*)d_in[0];
    const int* ei       = (const int*)d_in[1];
    const int* ea       = (const int*)d_in[2];
    const int* batch    = (const int*)d_in[3];
    const float* node_emb = (const float*)d_in[4];
    const float* edge_emb = (const float*)d_in[5];
    const float* Wq    = (const float*)d_in[6];
    const float* Wk    = (const float*)d_in[7];
    const float* Wv    = (const float*)d_in[8];
    const float* We    = (const float*)d_in[9];
    const float* Wskip = (const float*)d_in[10];
    const float* bq    = (const float*)d_in[11];
    const float* bk    = (const float*)d_in[12];
    const float* bv    = (const float*)d_in[13];
    const float* bskip = (const float*)d_in[14];
    const float* gate_W = (const float*)d_in[15];
    const float* gate_b = (const float*)d_in[16];
    const float* out_W  = (const float*)d_in[17];
    const float* out_b  = (const float*)d_in[18];
    float* out = (float*)d_out;

    const size_t NH = (size_t)N_NODES * H;
    float* ws   = (float*)d_ws;
    float* h    = ws;
    float* q    = h + NH;
    float* k    = q + NH;
    float* v    = k + NH;
    float* s    = v + NH;
    float* te   = s + NH;
    float* gate = te + LAYERS * 10 * H;
    int* deg       = (int*)(gate + N_NODES);
    int* row_start = deg + N_NODES;
    int* cursor    = row_start + N_NODES;
    int* packed    = cursor + N_NODES;
    unsigned* gmax = (unsigned*)(packed + N_EDGES);  // gmax, gden, outacc contiguous
    float* gden    = (float*)(gmax + NGRAPH);
    float* outacc  = gden + NGRAPH;

    // zero degree histogram
    hipMemsetAsync(deg, 0, N_NODES * sizeof(int), stream);

    k_init_h<<<(N_NODES * H + 255) / 256, 256, 0, stream>>>(x, node_emb, h);
    k_te<<<(LAYERS * 10 * H + 255) / 256, 256, 0, stream>>>(edge_emb, We, te);

    // CSR build (layer-invariant)
    k_hist<<<(N_EDGES + 255) / 256, 256, 0, stream>>>(ei, deg);
    k_scan<<<1, 1024, 0, stream>>>(deg, row_start, cursor);
    k_scatter<<<(N_EDGES + 255) / 256, 256, 0, stream>>>(ei, ea, cursor, packed);
    // after scatter: cursor[dst] == row end

    for (int l = 0; l < LAYERS; l++) {
        k_node_gemm<<<(N_NODES + 63) / 64, 256, 0, stream>>>(
            h,
            Wq + (size_t)l * H * H, Wk + (size_t)l * H * H,
            Wv + (size_t)l * H * H, Wskip + (size_t)l * H * H,
            bq + (size_t)l * H, bk + (size_t)l * H, bv + (size_t)l * H, bskip + (size_t)l * H,
            q, k, v, s);
        k_agg<<<(N_NODES + 3) / 4, 256, 0, stream>>>(
            row_start, cursor, packed, q, k, v, s, te + (size_t)l * 10 * H, h);
    }

    hipMemsetAsync(gmax, 0, (2 * (size_t)NGRAPH + (size_t)NGRAPH * OUTD) * sizeof(float), stream);
    k_gate<<<(N_NODES + 255) / 256, 256, 0, stream>>>(h, gate_W, gate_b, batch, gate, gmax);
    k_readout<<<(N_NODES * OUTD + 255) / 256, 256, 0, stream>>>(h, out_W, out_b, batch, gate, gmax, gden, outacc);
    k_final<<<(NGRAPH * OUTD + 255) / 256, 256, 0, stream>>>(outacc, gden, out);
}

// Round 5
// 896.235 us; speedup vs baseline: 10.0729x; 1.2049x over previous
//
#include <hip/hip_runtime.h>
#include <hip/hip_bf16.h>

#define N_NODES 50000
#define N_EDGES 800000
#define H 64
#define ED 32
#define LAYERS 3
#define NGRAPH 256
#define OUTD 32
#define SCALE 0.125f

// ---------------- init: h = node_emb[x] ----------------
__global__ void k_init_h(const int* __restrict__ x, const float* __restrict__ node_emb,
                         float* __restrict__ h) {
    int i = blockIdx.x * blockDim.x + threadIdx.x;
    if (i >= N_NODES * H) return;
    int n = i >> 6, c = i & 63;
    h[i] = node_emb[x[n] * H + c];
}

// ---------------- te[l][cat][c] = sum_d edge_emb[cat][d] * We[l][d][c] ----------------
__global__ void k_te(const float* __restrict__ edge_emb, const float* __restrict__ We,
                     float* __restrict__ te) {
    int i = blockIdx.x * blockDim.x + threadIdx.x;
    if (i >= LAYERS * 10 * H) return;
    int c = i & 63;
    int cat = (i >> 6) % 10;
    int l = i / (10 * H);
    float acc = 0.f;
    for (int d = 0; d < ED; d++)
        acc += edge_emb[cat * ED + d] * We[((size_t)l * ED + d) * H + c];
    te[i] = acc;
}

// ---------------- CSR build: histogram / scan / scatter ----------------
__global__ void k_hist(const int* __restrict__ ei, int* __restrict__ deg) {
    int e = blockIdx.x * blockDim.x + threadIdx.x;
    if (e >= N_EDGES) return;
    atomicAdd(&deg[ei[N_EDGES + e]], 1);
}

__global__ __launch_bounds__(1024) void k_scan(const int* __restrict__ deg,
                                               int* __restrict__ row_start,
                                               int* __restrict__ cursor) {
    __shared__ int part[1024];
    int t = threadIdx.x;
    const int CH = (N_NODES + 1023) / 1024;
    int lo = t * CH, hi = min(lo + CH, N_NODES);
    int sum = 0;
    for (int i = lo; i < hi; i++) sum += deg[i];
    part[t] = sum;
    __syncthreads();
    for (int off = 1; off < 1024; off <<= 1) {
        int add = (t >= off) ? part[t - off] : 0;
        __syncthreads();
        part[t] += add;
        __syncthreads();
    }
    int pre = (t == 0) ? 0 : part[t - 1];
    for (int i = lo; i < hi; i++) {
        row_start[i] = pre;
        cursor[i] = pre;
        pre += deg[i];
    }
}

__global__ void k_scatter(const int* __restrict__ ei, const int* __restrict__ ea,
                          int* __restrict__ cursor, int* __restrict__ packed) {
    int e = blockIdx.x * blockDim.x + threadIdx.x;
    if (e >= N_EDGES) return;
    int src = ei[e], dst = ei[N_EDGES + e], cat = ea[e];
    int pos = atomicAdd(&cursor[dst], 1);
    packed[pos] = src | (cat << 16);
}

// ---------------- graph bounds: gs[g] = lower_bound(batch, g) ----------------
__global__ void k_gbounds(const int* __restrict__ batch, int* __restrict__ gs) {
    int g = blockIdx.x * blockDim.x + threadIdx.x;
    if (g > NGRAPH) return;
    int lo = 0, hi = N_NODES;
    while (lo < hi) {
        int mid = (lo + hi) >> 1;
        if (batch[mid] < g) lo = mid + 1; else hi = mid;
    }
    gs[g] = lo;
}

// ---------------- fused node GEMM: q,k,v,skip = h @ W* + b* ----------------
__global__ __launch_bounds__(256) void k_node_gemm(
    const float* __restrict__ h,
    const float* __restrict__ Wq, const float* __restrict__ Wk,
    const float* __restrict__ Wv, const float* __restrict__ Wsk,
    const float* __restrict__ bq, const float* __restrict__ bk,
    const float* __restrict__ bv, const float* __restrict__ bsk,
    float* __restrict__ q, float* __restrict__ k, float* __restrict__ v, float* __restrict__ s)
{
    __shared__ float wts[4][64][32];
    __shared__ float hr[64][65];
    int tid = threadIdx.x;
    int base = blockIdx.x * 64;
    for (int i = tid; i < 64 * 64; i += 256) {
        int r = i >> 6, c = i & 63;
        int n = base + r;
        hr[r][c] = (n < N_NODES) ? h[(size_t)n * H + c] : 0.f;
    }
    for (int ch = 0; ch < 2; ch++) {
        __syncthreads();
        for (int i = tid; i < 64 * 32; i += 256) {
            int r = i >> 5, c = i & 31;
            int off = r * H + ch * 32 + c;
            wts[0][r][c] = Wq[off];
            wts[1][r][c] = Wk[off];
            wts[2][r][c] = Wv[off];
            wts[3][r][c] = Wsk[off];
        }
        __syncthreads();
        int c = tid & 31, ln = tid >> 5;
        float b0 = bq[ch * 32 + c], b1 = bk[ch * 32 + c];
        float b2 = bv[ch * 32 + c], b3 = bsk[ch * 32 + c];
        for (int r0 = 0; r0 < 64; r0 += 8) {
            int r = r0 + ln;
            int n = base + r;
            if (n < N_NODES) {
                float a0 = 0.f, a1 = 0.f, a2 = 0.f, a3 = 0.f;
                #pragma unroll
                for (int kk = 0; kk < 64; kk++) {
                    float hv = hr[r][kk];
                    a0 += hv * wts[0][kk][c];
                    a1 += hv * wts[1][kk][c];
                    a2 += hv * wts[2][kk][c];
                    a3 += hv * wts[3][kk][c];
                }
                size_t o = (size_t)n * H + ch * 32 + c;
                q[o] = a0 + b0; k[o] = a1 + b1; v[o] = a2 + b2; s[o] = a3 + b3;
            }
        }
    }
}

// ---------------- fused gather: alpha + online softmax + agg + skip + relu ----------------
__global__ __launch_bounds__(256) void k_agg(
    const int* __restrict__ row_start, const int* __restrict__ row_end,
    const int* __restrict__ packed,
    const float* __restrict__ q, const float* __restrict__ k,
    const float* __restrict__ v, const float* __restrict__ s,
    const float* __restrict__ te, float* __restrict__ h)
{
    __shared__ float tel[10 * 64];
    for (int i = threadIdx.x; i < 10 * 64; i += 256) tel[i] = te[i];
    __syncthreads();
    int wave = threadIdx.x >> 6;
    int lane = threadIdx.x & 63;
    int dst = blockIdx.x * 4 + wave;
    if (dst >= N_NODES) return;
    int beg = row_start[dst], end = row_end[dst];
    float qv = q[(size_t)dst * H + lane];
    float m = -INFINITY, l = 0.f, acc = 0.f;
    for (int p0 = beg; p0 < end; p0 += 64) {
        int pk = (p0 + lane < end) ? packed[p0 + lane] : 0;
        int cnt = min(64, end - p0);
        for (int i = 0; i < cnt; i++) {
            int pkt = __shfl(pk, i);
            int src = pkt & 0xFFFF;
            int cat = pkt >> 16;
            float t = tel[cat * 64 + lane];
            // issue both row loads before the dependent shuffle chain
            float kv = k[(size_t)src * H + lane] + t;
            float vv = v[(size_t)src * H + lane] + t;
            float part = qv * kv;
            #pragma unroll
            for (int d = 1; d < 64; d <<= 1) part += __shfl_xor(part, d);
            float a = part * SCALE;
            float mn = fmaxf(m, a);
            float corr = __expf(m - mn);
            float w = __expf(a - mn);
            acc = acc * corr + w * vv;
            l = l * corr + w;
            m = mn;
        }
    }
    float outv = (l > 0.f) ? acc / l : 0.f;
    float r = outv + s[(size_t)dst * H + lane];
    h[(size_t)dst * H + lane] = fmaxf(r, 0.f);
}

// ---------------- readout gate: gate = h @ gate_W + b ----------------
__global__ void k_gate(const float* __restrict__ h, const float* __restrict__ gW,
                       const float* __restrict__ gb, const int* __restrict__ batch,
                       float* __restrict__ gate)
{
    int n = blockIdx.x * blockDim.x + threadIdx.x;
    if (n >= N_NODES) return;
    float acc = gb[0];
    const float* hp = h + (size_t)n * H;
    #pragma unroll
    for (int i = 0; i < H; i++) acc += hp[i] * gW[i];
    gate[n] = acc;
}

// ---------------- fused per-graph readout: max, exp-weighted sum, divide ----------------
// one block per graph; thread = ln*32 + o, ln in [0,8), o in [0,32)
__global__ __launch_bounds__(256) void k_readout2(
    const float* __restrict__ h, const float* __restrict__ oW,
    const float* __restrict__ ob, const float* __restrict__ gate,
    const int* __restrict__ gs, float* __restrict__ out)
{
    __shared__ float wls[H * OUTD];
    __shared__ float hs[8][H + 1];
    __shared__ float red[256];
    __shared__ float den_s[8];
    __shared__ float gmax_s, den_tot;
    int t = threadIdx.x;
    int g = blockIdx.x;
    for (int i = t; i < H * OUTD; i += 256) wls[i] = oW[i];
    int beg = gs[g], end = gs[g + 1];
    // pass 1: per-graph gate max
    float mx = -INFINITY;
    for (int n = beg + t; n < end; n += 256) mx = fmaxf(mx, gate[n]);
    red[t] = mx;
    __syncthreads();
    for (int sft = 128; sft > 0; sft >>= 1) {
        if (t < sft) red[t] = fmaxf(red[t], red[t + sft]);
        __syncthreads();
    }
    if (t == 0) gmax_s = red[0];
    __syncthreads();
    float gm = gmax_s;
    int ln = t >> 5, o = t & 31;
    float acc = 0.f, den = 0.f;
    for (int n0 = beg; n0 < end; n0 += 8) {
        __syncthreads();
        for (int i = t; i < 8 * H; i += 256) {
            int r = i >> 6, c = i & 63;
            int n = n0 + r;
            hs[r][c] = (n < end) ? h[(size_t)n * H + c] : 0.f;
        }
        __syncthreads();
        int n = n0 + ln;
        if (n < end) {
            float wt = __expf(gate[n] - gm);
            float d0 = 0.f;
            #pragma unroll
            for (int i = 0; i < H; i++) d0 += hs[ln][i] * wls[i * OUTD + o];
            acc += wt * d0;
            if (o == 0) den += wt;
        }
    }
    __syncthreads();
    red[t] = acc;
    if (o == 0) den_s[ln] = den;
    __syncthreads();
    for (int sft = 4; sft >= 1; sft >>= 1) {
        if (ln < sft) red[t] += red[t + sft * 32];
        __syncthreads();
    }
    if (t == 0) {
        float dt = 0.f;
        #pragma unroll
        for (int i = 0; i < 8; i++) dt += den_s[i];
        den_tot = dt;
    }
    __syncthreads();
    if (ln == 0) {
        float dt = den_tot;
        out[g * OUTD + o] = (dt > 0.f) ? red[o] / dt + ob[o] : 0.f;
    }
}

extern "C" void kernel_launch(void* const* d_in, const int* in_sizes, int n_in,
                              void* d_out, int out_size, void* d_ws, size_t ws_size,
                              hipStream_t stream)
{
    const int* x        = (const int*)d_in[0];
    const int* ei       = (const int*)d_in[1];
    const int* ea       = (const int*)d_in[2];
    const int* batch    = (const int*)d_in[3];
    const float* node_emb = (const float*)d_in[4];
    const float* edge_emb = (const float*)d_in[5];
    const float* Wq    = (const float*)d_in[6];
    const float* Wk    = (const float*)d_in[7];
    const float* Wv    = (const float*)d_in[8];
    const float* We    = (const float*)d_in[9];
    const float* Wskip = (const float*)d_in[10];
    const float* bq    = (const float*)d_in[11];
    const float* bk    = (const float*)d_in[12];
    const float* bv    = (const float*)d_in[13];
    const float* bskip = (const float*)d_in[14];
    const float* gate_W = (const float*)d_in[15];
    const float* gate_b = (const float*)d_in[16];
    const float* out_W  = (const float*)d_in[17];
    const float* out_b  = (const float*)d_in[18];
    float* out = (float*)d_out;

    const size_t NH = (size_t)N_NODES * H;
    float* ws   = (float*)d_ws;
    float* h    = ws;
    float* q    = h + NH;
    float* k    = q + NH;
    float* v    = k + NH;
    float* s    = v + NH;
    float* te   = s + NH;
    float* gate = te + LAYERS * 10 * H;
    int* deg       = (int*)(gate + N_NODES);
    int* row_start = deg + N_NODES;
    int* cursor    = row_start + N_NODES;
    int* packed    = cursor + N_NODES;
    int* gs        = packed + N_EDGES;   // 257 ints

    hipMemsetAsync(deg, 0, N_NODES * sizeof(int), stream);

    k_init_h<<<(N_NODES * H + 255) / 256, 256, 0, stream>>>(x, node_emb, h);
    k_te<<<(LAYERS * 10 * H + 255) / 256, 256, 0, stream>>>(edge_emb, We, te);

    // CSR build (layer-invariant)
    k_hist<<<(N_EDGES + 255) / 256, 256, 0, stream>>>(ei, deg);
    k_scan<<<1, 1024, 0, stream>>>(deg, row_start, cursor);
    k_scatter<<<(N_EDGES + 255) / 256, 256, 0, stream>>>(ei, ea, cursor, packed);
    k_gbounds<<<2, 256, 0, stream>>>(batch, gs);

    for (int l = 0; l < LAYERS; l++) {
        k_node_gemm<<<(N_NODES + 63) / 64, 256, 0, stream>>>(
            h,
            Wq + (size_t)l * H * H, Wk + (size_t)l * H * H,
            Wv + (size_t)l * H * H, Wskip + (size_t)l * H * H,
            bq + (size_t)l * H, bk + (size_t)l * H, bv + (size_t)l * H, bskip + (size_t)l * H,
            q, k, v, s);
        k_agg<<<(N_NODES + 3) / 4, 256, 0, stream>>>(
            row_start, cursor, packed, q, k, v, s, te + (size_t)l * 10 * H, h);
    }

    k_gate<<<(N_NODES + 255) / 256, 256, 0, stream>>>(h, gate_W, gate_b, batch, gate);
    k_readout2<<<NGRAPH, 256, 0, stream>>>(h, out_W, out_b, gate, gs, out);
}

// Round 6
// 796.268 us; speedup vs baseline: 11.3375x; 1.1255x over previous
//
#include <hip/hip_runtime.h>
#include <hip/hip_bf16.h>

#define N_NODES 50000
#define N_EDGES 800000
#define H 64
#define ED 32
#define LAYERS 3
#define NGRAPH 256
#define OUTD 32
#define SCALE 0.125f
#define SCAN_NB ((N_NODES + 255) / 256)   // 196

// ---------------- init: h = node_emb[x] ----------------
__global__ void k_init_h(const int* __restrict__ x, const float* __restrict__ node_emb,
                         float* __restrict__ h) {
    int i = blockIdx.x * blockDim.x + threadIdx.x;
    if (i >= N_NODES * H) return;
    int n = i >> 6, c = i & 63;
    h[i] = node_emb[x[n] * H + c];
}

// ---------------- te[l][cat][c] = sum_d edge_emb[cat][d] * We[l][d][c] ----------------
__global__ void k_te(const float* __restrict__ edge_emb, const float* __restrict__ We,
                     float* __restrict__ te) {
    int i = blockIdx.x * blockDim.x + threadIdx.x;
    if (i >= LAYERS * 10 * H) return;
    int c = i & 63;
    int cat = (i >> 6) % 10;
    int l = i / (10 * H);
    float acc = 0.f;
    for (int d = 0; d < ED; d++)
        acc += edge_emb[cat * ED + d] * We[((size_t)l * ED + d) * H + c];
    te[i] = acc;
}

// ---------------- CSR build: histogram / 3-phase scan / scatter ----------------
__global__ void k_hist(const int* __restrict__ ei, int* __restrict__ deg) {
    int e = blockIdx.x * blockDim.x + threadIdx.x;
    if (e >= N_EDGES) return;
    atomicAdd(&deg[ei[N_EDGES + e]], 1);
}

// phase 1: per-block sums of deg (coalesced)
__global__ __launch_bounds__(256) void k_scan1(const int* __restrict__ deg, int* __restrict__ bsum) {
    __shared__ int red[256];
    int t = threadIdx.x;
    int i = blockIdx.x * 256 + t;
    red[t] = (i < N_NODES) ? deg[i] : 0;
    __syncthreads();
    for (int s = 128; s > 0; s >>= 1) {
        if (t < s) red[t] += red[t + s];
        __syncthreads();
    }
    if (t == 0) bsum[blockIdx.x] = red[0];
}

// phase 2: exclusive scan of the 196 block sums (single small block)
__global__ __launch_bounds__(256) void k_scan2(const int* __restrict__ bsum, int* __restrict__ boff) {
    __shared__ int part[256];
    int t = threadIdx.x;
    part[t] = (t < SCAN_NB) ? bsum[t] : 0;
    __syncthreads();
    for (int off = 1; off < 256; off <<= 1) {
        int add = (t >= off) ? part[t - off] : 0;
        __syncthreads();
        part[t] += add;
        __syncthreads();
    }
    boff[t] = (t == 0) ? 0 : part[t - 1];
}

// phase 3: local exclusive scan + block offset -> row_start, cursor (coalesced)
__global__ __launch_bounds__(256) void k_scan3(const int* __restrict__ deg, const int* __restrict__ boff,
                                               int* __restrict__ row_start, int* __restrict__ cursor) {
    __shared__ int part[256];
    int t = threadIdx.x;
    int i = blockIdx.x * 256 + t;
    int v = (i < N_NODES) ? deg[i] : 0;
    part[t] = v;
    __syncthreads();
    for (int off = 1; off < 256; off <<= 1) {
        int add = (t >= off) ? part[t - off] : 0;
        __syncthreads();
        part[t] += add;
        __syncthreads();
    }
    if (i < N_NODES) {
        int excl = part[t] - v + boff[blockIdx.x];
        row_start[i] = excl;
        cursor[i] = excl;
    }
}

__global__ void k_scatter(const int* __restrict__ ei, const int* __restrict__ ea,
                          int* __restrict__ cursor, int* __restrict__ packed) {
    int e = blockIdx.x * blockDim.x + threadIdx.x;
    if (e >= N_EDGES) return;
    int src = ei[e], dst = ei[N_EDGES + e], cat = ea[e];
    int pos = atomicAdd(&cursor[dst], 1);
    packed[pos] = src | (cat << 16);
}

// ---------------- graph bounds: gs[g] = lower_bound(batch, g) ----------------
__global__ void k_gbounds(const int* __restrict__ batch, int* __restrict__ gs) {
    int g = blockIdx.x * blockDim.x + threadIdx.x;
    if (g > NGRAPH) return;
    int lo = 0, hi = N_NODES;
    while (lo < hi) {
        int mid = (lo + hi) >> 1;
        if (batch[mid] < g) lo = mid + 1; else hi = mid;
    }
    gs[g] = lo;
}

// ---------------- fused node GEMM: q,k,v,skip = h @ W* + b* ----------------
__global__ __launch_bounds__(256) void k_node_gemm(
    const float* __restrict__ h,
    const float* __restrict__ Wq, const float* __restrict__ Wk,
    const float* __restrict__ Wv, const float* __restrict__ Wsk,
    const float* __restrict__ bq, const float* __restrict__ bk,
    const float* __restrict__ bv, const float* __restrict__ bsk,
    float* __restrict__ q, float* __restrict__ k, float* __restrict__ v, float* __restrict__ s)
{
    __shared__ float wts[4][64][32];
    __shared__ float hr[64][65];
    int tid = threadIdx.x;
    int base = blockIdx.x * 64;
    for (int i = tid; i < 64 * 64; i += 256) {
        int r = i >> 6, c = i & 63;
        int n = base + r;
        hr[r][c] = (n < N_NODES) ? h[(size_t)n * H + c] : 0.f;
    }
    for (int ch = 0; ch < 2; ch++) {
        __syncthreads();
        for (int i = tid; i < 64 * 32; i += 256) {
            int r = i >> 5, c = i & 31;
            int off = r * H + ch * 32 + c;
            wts[0][r][c] = Wq[off];
            wts[1][r][c] = Wk[off];
            wts[2][r][c] = Wv[off];
            wts[3][r][c] = Wsk[off];
        }
        __syncthreads();
        int c = tid & 31, ln = tid >> 5;
        float b0 = bq[ch * 32 + c], b1 = bk[ch * 32 + c];
        float b2 = bv[ch * 32 + c], b3 = bsk[ch * 32 + c];
        for (int r0 = 0; r0 < 64; r0 += 8) {
            int r = r0 + ln;
            int n = base + r;
            if (n < N_NODES) {
                float a0 = 0.f, a1 = 0.f, a2 = 0.f, a3 = 0.f;
                #pragma unroll
                for (int kk = 0; kk < 64; kk++) {
                    float hv = hr[r][kk];
                    a0 += hv * wts[0][kk][c];
                    a1 += hv * wts[1][kk][c];
                    a2 += hv * wts[2][kk][c];
                    a3 += hv * wts[3][kk][c];
                }
                size_t o = (size_t)n * H + ch * 32 + c;
                q[o] = a0 + b0; k[o] = a1 + b1; v[o] = a2 + b2; s[o] = a3 + b3;
            }
        }
    }
}

// ---------------- fused gather: alpha + online softmax + agg + skip + relu ----------------
__global__ __launch_bounds__(256) void k_agg(
    const int* __restrict__ row_start, const int* __restrict__ row_end,
    const int* __restrict__ packed,
    const float* __restrict__ q, const float* __restrict__ k,
    const float* __restrict__ v, const float* __restrict__ s,
    const float* __restrict__ te, float* __restrict__ h)
{
    __shared__ float tel[10 * 64];
    for (int i = threadIdx.x; i < 10 * 64; i += 256) tel[i] = te[i];
    __syncthreads();
    int wave = threadIdx.x >> 6;
    int lane = threadIdx.x & 63;
    int dst = blockIdx.x * 4 + wave;
    if (dst >= N_NODES) return;
    int beg = row_start[dst], end = row_end[dst];
    float qv = q[(size_t)dst * H + lane];
    float m = -INFINITY, l = 0.f, acc = 0.f;
    for (int p0 = beg; p0 < end; p0 += 64) {
        int pk = (p0 + lane < end) ? packed[p0 + lane] : 0;
        int cnt = min(64, end - p0);
        for (int i = 0; i < cnt; i++) {
            int pkt = __shfl(pk, i);
            int src = pkt & 0xFFFF;
            int cat = pkt >> 16;
            float t = tel[cat * 64 + lane];
            float kv = k[(size_t)src * H + lane] + t;
            float vv = v[(size_t)src * H + lane] + t;
            float part = qv * kv;
            #pragma unroll
            for (int d = 1; d < 64; d <<= 1) part += __shfl_xor(part, d);
            float a = part * SCALE;
            float mn = fmaxf(m, a);
            float corr = __expf(m - mn);
            float w = __expf(a - mn);
            acc = acc * corr + w * vv;
            l = l * corr + w;
            m = mn;
        }
    }
    float outv = (l > 0.f) ? acc / l : 0.f;
    float r = outv + s[(size_t)dst * H + lane];
    h[(size_t)dst * H + lane] = fmaxf(r, 0.f);
}

// ---------------- readout gate: gate = h @ gate_W + b ----------------
__global__ void k_gate(const float* __restrict__ h, const float* __restrict__ gW,
                       const float* __restrict__ gb, const int* __restrict__ batch,
                       float* __restrict__ gate)
{
    int n = blockIdx.x * blockDim.x + threadIdx.x;
    if (n >= N_NODES) return;
    float acc = gb[0];
    const float* hp = h + (size_t)n * H;
    #pragma unroll
    for (int i = 0; i < H; i++) acc += hp[i] * gW[i];
    gate[n] = acc;
}

// ---------------- fused per-graph readout ----------------
__global__ __launch_bounds__(256) void k_readout2(
    const float* __restrict__ h, const float* __restrict__ oW,
    const float* __restrict__ ob, const float* __restrict__ gate,
    const int* __restrict__ gs, float* __restrict__ out)
{
    __shared__ float wls[H * OUTD];
    __shared__ float hs[8][H + 1];
    __shared__ float red[256];
    __shared__ float den_s[8];
    __shared__ float gmax_s, den_tot;
    int t = threadIdx.x;
    int g = blockIdx.x;
    for (int i = t; i < H * OUTD; i += 256) wls[i] = oW[i];
    int beg = gs[g], end = gs[g + 1];
    float mx = -INFINITY;
    for (int n = beg + t; n < end; n += 256) mx = fmaxf(mx, gate[n]);
    red[t] = mx;
    __syncthreads();
    for (int sft = 128; sft > 0; sft >>= 1) {
        if (t < sft) red[t] = fmaxf(red[t], red[t + sft]);
        __syncthreads();
    }
    if (t == 0) gmax_s = red[0];
    __syncthreads();
    float gm = gmax_s;
    int ln = t >> 5, o = t & 31;
    float acc = 0.f, den = 0.f;
    for (int n0 = beg; n0 < end; n0 += 8) {
        __syncthreads();
        for (int i = t; i < 8 * H; i += 256) {
            int r = i >> 6, c = i & 63;
            int n = n0 + r;
            hs[r][c] = (n < end) ? h[(size_t)n * H + c] : 0.f;
        }
        __syncthreads();
        int n = n0 + ln;
        if (n < end) {
            float wt = __expf(gate[n] - gm);
            float d0 = 0.f;
            #pragma unroll
            for (int i = 0; i < H; i++) d0 += hs[ln][i] * wls[i * OUTD + o];
            acc += wt * d0;
            if (o == 0) den += wt;
        }
    }
    __syncthreads();
    red[t] = acc;
    if (o == 0) den_s[ln] = den;
    __syncthreads();
    for (int sft = 4; sft >= 1; sft >>= 1) {
        if (ln < sft) red[t] += red[t + sft * 32];
        __syncthreads();
    }
    if (t == 0) {
        float dt = 0.f;
        #pragma unroll
        for (int i = 0; i < 8; i++) dt += den_s[i];
        den_tot = dt;
    }
    __syncthreads();
    if (ln == 0) {
        float dt = den_tot;
        out[g * OUTD + o] = (dt > 0.f) ? red[o] / dt + ob[o] : 0.f;
    }
}

extern "C" void kernel_launch(void* const* d_in, const int* in_sizes, int n_in,
                              void* d_out, int out_size, void* d_ws, size_t ws_size,
                              hipStream_t stream)
{
    const int* x        = (const int*)d_in[0];
    const int* ei       = (const int*)d_in[1];
    const int* ea       = (const int*)d_in[2];
    const int* batch    = (const int*)d_in[3];
    const float* node_emb = (const float*)d_in[4];
    const float* edge_emb = (const float*)d_in[5];
    const float* Wq    = (const float*)d_in[6];
    const float* Wk    = (const float*)d_in[7];
    const float* Wv    = (const float*)d_in[8];
    const float* We    = (const float*)d_in[9];
    const float* Wskip = (const float*)d_in[10];
    const float* bq    = (const float*)d_in[11];
    const float* bk    = (const float*)d_in[12];
    const float* bv    = (const float*)d_in[13];
    const float* bskip = (const float*)d_in[14];
    const float* gate_W = (const float*)d_in[15];
    const float* gate_b = (const float*)d_in[16];
    const float* out_W  = (const float*)d_in[17];
    const float* out_b  = (const float*)d_in[18];
    float* out = (float*)d_out;

    const size_t NH = (size_t)N_NODES * H;
    float* ws   = (float*)d_ws;
    float* h    = ws;
    float* q    = h + NH;
    float* k    = q + NH;
    float* v    = k + NH;
    float* s    = v + NH;
    float* te   = s + NH;
    float* gate = te + LAYERS * 10 * H;
    int* deg       = (int*)(gate + N_NODES);
    int* row_start = deg + N_NODES;
    int* cursor    = row_start + N_NODES;
    int* packed    = cursor + N_NODES;
    int* gs        = packed + N_EDGES;   // 257 ints
    int* bsum      = gs + NGRAPH + 1;    // 196
    int* boff      = bsum + 256;         // 256

    hipMemsetAsync(deg, 0, N_NODES * sizeof(int), stream);

    k_init_h<<<(N_NODES * H + 255) / 256, 256, 0, stream>>>(x, node_emb, h);
    k_te<<<(LAYERS * 10 * H + 255) / 256, 256, 0, stream>>>(edge_emb, We, te);

    // CSR build (layer-invariant)
    k_hist<<<(N_EDGES + 255) / 256, 256, 0, stream>>>(ei, deg);
    k_scan1<<<SCAN_NB, 256, 0, stream>>>(deg, bsum);
    k_scan2<<<1, 256, 0, stream>>>(bsum, boff);
    k_scan3<<<SCAN_NB, 256, 0, stream>>>(deg, boff, row_start, cursor);
    k_scatter<<<(N_EDGES + 255) / 256, 256, 0, stream>>>(ei, ea, cursor, packed);
    k_gbounds<<<2, 256, 0, stream>>>(batch, gs);

    for (int l = 0; l < LAYERS; l++) {
        k_node_gemm<<<(N_NODES + 63) / 64, 256, 0, stream>>>(
            h,
            Wq + (size_t)l * H * H, Wk + (size_t)l * H * H,
            Wv + (size_t)l * H * H, Wskip + (size_t)l * H * H,
            bq + (size_t)l * H, bk + (size_t)l * H, bv + (size_t)l * H, bskip + (size_t)l * H,
            q, k, v, s);
        k_agg<<<(N_NODES + 3) / 4, 256, 0, stream>>>(
            row_start, cursor, packed, q, k, v, s, te + (size_t)l * 10 * H, h);
    }

    k_gate<<<(N_NODES + 255) / 256, 256, 0, stream>>>(h, gate_W, gate_b, batch, gate);
    k_readout2<<<NGRAPH, 256, 0, stream>>>(h, out_W, out_b, gate, gs, out);
}

// Round 7
// 710.782 us; speedup vs baseline: 12.7010x; 1.1203x over previous
//
#include <hip/hip_runtime.h>
#include <hip/hip_bf16.h>

#define N_NODES 50000
#define N_EDGES 800000
#define H 64
#define ED 32
#define LAYERS 3
#define NGRAPH 256
#define OUTD 32
#define SCALE 0.125f
#define SCAN_NB ((N_NODES + 255) / 256)   // 196

// wave64 sum via DPP (VALU pipe, no LDS): row_shr 1/2/4/8 + row_bcast15/31 -> lane63
__device__ __forceinline__ float wave_sum64(float x) {
    x += __int_as_float(__builtin_amdgcn_update_dpp(0, __float_as_int(x), 0x111, 0xf, 0xf, true));
    x += __int_as_float(__builtin_amdgcn_update_dpp(0, __float_as_int(x), 0x112, 0xf, 0xf, true));
    x += __int_as_float(__builtin_amdgcn_update_dpp(0, __float_as_int(x), 0x114, 0xf, 0xf, true));
    x += __int_as_float(__builtin_amdgcn_update_dpp(0, __float_as_int(x), 0x118, 0xf, 0xf, true));
    x += __int_as_float(__builtin_amdgcn_update_dpp(0, __float_as_int(x), 0x142, 0xa, 0xf, true));
    x += __int_as_float(__builtin_amdgcn_update_dpp(0, __float_as_int(x), 0x143, 0xc, 0xf, true));
    return __int_as_float(__builtin_amdgcn_readlane(__float_as_int(x), 63));
}

// ---------------- init: h = node_emb[x] ----------------
__global__ void k_init_h(const int* __restrict__ x, const float* __restrict__ node_emb,
                         float* __restrict__ h) {
    int i = blockIdx.x * blockDim.x + threadIdx.x;
    if (i >= N_NODES * H) return;
    int n = i >> 6, c = i & 63;
    h[i] = node_emb[x[n] * H + c];
}

// ---------------- te[l][cat][c] ----------------
__global__ void k_te(const float* __restrict__ edge_emb, const float* __restrict__ We,
                     float* __restrict__ te) {
    int i = blockIdx.x * blockDim.x + threadIdx.x;
    if (i >= LAYERS * 10 * H) return;
    int c = i & 63;
    int cat = (i >> 6) % 10;
    int l = i / (10 * H);
    float acc = 0.f;
    for (int d = 0; d < ED; d++)
        acc += edge_emb[cat * ED + d] * We[((size_t)l * ED + d) * H + c];
    te[i] = acc;
}

// ---------------- CSR build ----------------
__global__ void k_hist(const int* __restrict__ ei, int* __restrict__ deg) {
    int e = blockIdx.x * blockDim.x + threadIdx.x;
    if (e >= N_EDGES) return;
    atomicAdd(&deg[ei[N_EDGES + e]], 1);
}

__global__ __launch_bounds__(256) void k_scan1(const int* __restrict__ deg, int* __restrict__ bsum) {
    __shared__ int red[256];
    int t = threadIdx.x;
    int i = blockIdx.x * 256 + t;
    red[t] = (i < N_NODES) ? deg[i] : 0;
    __syncthreads();
    for (int s = 128; s > 0; s >>= 1) {
        if (t < s) red[t] += red[t + s];
        __syncthreads();
    }
    if (t == 0) bsum[blockIdx.x] = red[0];
}

__global__ __launch_bounds__(256) void k_scan2(const int* __restrict__ bsum, int* __restrict__ boff) {
    __shared__ int part[256];
    int t = threadIdx.x;
    part[t] = (t < SCAN_NB) ? bsum[t] : 0;
    __syncthreads();
    for (int off = 1; off < 256; off <<= 1) {
        int add = (t >= off) ? part[t - off] : 0;
        __syncthreads();
        part[t] += add;
        __syncthreads();
    }
    boff[t] = (t == 0) ? 0 : part[t - 1];
}

__global__ __launch_bounds__(256) void k_scan3(const int* __restrict__ deg, const int* __restrict__ boff,
                                               int* __restrict__ row_start, int* __restrict__ cursor) {
    __shared__ int part[256];
    int t = threadIdx.x;
    int i = blockIdx.x * 256 + t;
    int v = (i < N_NODES) ? deg[i] : 0;
    part[t] = v;
    __syncthreads();
    for (int off = 1; off < 256; off <<= 1) {
        int add = (t >= off) ? part[t - off] : 0;
        __syncthreads();
        part[t] += add;
        __syncthreads();
    }
    if (i < N_NODES) {
        int excl = part[t] - v + boff[blockIdx.x];
        row_start[i] = excl;
        cursor[i] = excl;
    }
}

__global__ void k_scatter(const int* __restrict__ ei, const int* __restrict__ ea,
                          int* __restrict__ cursor, int* __restrict__ packed) {
    int e = blockIdx.x * blockDim.x + threadIdx.x;
    if (e >= N_EDGES) return;
    int src = ei[e], dst = ei[N_EDGES + e], cat = ea[e];
    int pos = atomicAdd(&cursor[dst], 1);
    packed[pos] = src | (cat << 16);
}

// ---------------- graph bounds ----------------
__global__ void k_gbounds(const int* __restrict__ batch, int* __restrict__ gs) {
    int g = blockIdx.x * blockDim.x + threadIdx.x;
    if (g > NGRAPH) return;
    int lo = 0, hi = N_NODES;
    while (lo < hi) {
        int mid = (lo + hi) >> 1;
        if (batch[mid] < g) lo = mid + 1; else hi = mid;
    }
    gs[g] = lo;
}

// ---------------- node GEMM: wave = matrix, lane = col, weights in VGPRs, no LDS --------
// q -> q[], k -> kv[n][0:64], v -> kv[n][64:128], skip -> s[]
__global__ __launch_bounds__(256) void k_node_gemm(
    const float* __restrict__ h,
    const float* __restrict__ Wq, const float* __restrict__ Wk,
    const float* __restrict__ Wv, const float* __restrict__ Wsk,
    const float* __restrict__ bq, const float* __restrict__ bk,
    const float* __restrict__ bv, const float* __restrict__ bsk,
    float* __restrict__ q, float* __restrict__ kv, float* __restrict__ s)
{
    int wvi = threadIdx.x >> 6, lane = threadIdx.x & 63;
    const float* Wm = (wvi == 0) ? Wq : (wvi == 1) ? Wk : (wvi == 2) ? Wv : Wsk;
    const float* bm = (wvi == 0) ? bq : (wvi == 1) ? bk : (wvi == 2) ? bv : bsk;
    float wcol[64];
    #pragma unroll 16
    for (int kk = 0; kk < 64; kk++) wcol[kk] = Wm[kk * H + lane];
    float bias = bm[lane];
    int base = blockIdx.x * 64;
    int nEnd = min(base + 64, N_NODES);
    if (base >= nEnd) return;
    float hv = h[(size_t)base * H + lane];       // prefetch first row
    for (int n = base; n < nEnd; n++) {
        float hcur = hv;
        int nn = min(n + 1, nEnd - 1);
        hv = h[(size_t)nn * H + lane];           // prefetch next row
        float acc = bias;
        #pragma unroll
        for (int kk = 0; kk < 64; kk++) {
            float hb = __int_as_float(__builtin_amdgcn_readlane(__float_as_int(hcur), kk));
            acc = fmaf(hb, wcol[kk], acc);
        }
        if (wvi == 0)      q[(size_t)n * H + lane] = acc;
        else if (wvi == 3) s[(size_t)n * H + lane] = acc;
        else               kv[(size_t)n * 2 * H + (size_t)(wvi - 1) * H + lane] = acc;
    }
}

// ---------------- fused gather: online softmax, DPP reduce, no bpermute ----------------
__global__ __launch_bounds__(256) void k_agg(
    const int* __restrict__ row_start, const int* __restrict__ row_end,
    const int* __restrict__ packed,
    const float* __restrict__ q, const float* __restrict__ kv,
    const float* __restrict__ s,
    const float* __restrict__ te, float* __restrict__ h)
{
    __shared__ float tel[10 * 64];
    for (int i = threadIdx.x; i < 10 * 64; i += 256) tel[i] = te[i];
    __syncthreads();
    int wave = threadIdx.x >> 6;
    int lane = threadIdx.x & 63;
    int dst = blockIdx.x * 4 + wave;
    if (dst >= N_NODES) return;
    int beg = row_start[dst], end = row_end[dst];
    float qv = q[(size_t)dst * H + lane];
    float m = -INFINITY, l = 0.f, acc = 0.f;
    for (int p0 = beg; p0 < end; p0 += 64) {
        int pk = (p0 + lane < end) ? packed[p0 + lane] : 0;
        int cnt = min(64, end - p0);
        for (int i = 0; i < cnt; i++) {
            int pkt = __builtin_amdgcn_readlane(pk, i);
            int src = pkt & 0xFFFF;
            int cat = pkt >> 16;
            float t = tel[cat * 64 + lane];
            const float* kvp = kv + (size_t)src * 2 * H;
            float kvv = kvp[lane] + t;
            float vv  = kvp[H + lane] + t;
            float a = wave_sum64(qv * kvv) * SCALE;
            float mn = fmaxf(m, a);
            float corr = __expf(m - mn);
            float w = __expf(a - mn);
            acc = acc * corr + w * vv;
            l = l * corr + w;
            m = mn;
        }
    }
    float outv = (l > 0.f) ? acc / l : 0.f;
    float r = outv + s[(size_t)dst * H + lane];
    h[(size_t)dst * H + lane] = fmaxf(r, 0.f);
}

// ---------------- readout gate ----------------
__global__ void k_gate(const float* __restrict__ h, const float* __restrict__ gW,
                       const float* __restrict__ gb, const int* __restrict__ batch,
                       float* __restrict__ gate)
{
    int n = blockIdx.x * blockDim.x + threadIdx.x;
    if (n >= N_NODES) return;
    float acc = gb[0];
    const float* hp = h + (size_t)n * H;
    #pragma unroll
    for (int i = 0; i < H; i++) acc += hp[i] * gW[i];
    gate[n] = acc;
}

// ---------------- fused per-graph readout ----------------
__global__ __launch_bounds__(256) void k_readout2(
    const float* __restrict__ h, const float* __restrict__ oW,
    const float* __restrict__ ob, const float* __restrict__ gate,
    const int* __restrict__ gs, float* __restrict__ out)
{
    __shared__ float wls[H * OUTD];
    __shared__ float hs[8][H + 1];
    __shared__ float red[256];
    __shared__ float den_s[8];
    __shared__ float gmax_s, den_tot;
    int t = threadIdx.x;
    int g = blockIdx.x;
    for (int i = t; i < H * OUTD; i += 256) wls[i] = oW[i];
    int beg = gs[g], end = gs[g + 1];
    float mx = -INFINITY;
    for (int n = beg + t; n < end; n += 256) mx = fmaxf(mx, gate[n]);
    red[t] = mx;
    __syncthreads();
    for (int sft = 128; sft > 0; sft >>= 1) {
        if (t < sft) red[t] = fmaxf(red[t], red[t + sft]);
        __syncthreads();
    }
    if (t == 0) gmax_s = red[0];
    __syncthreads();
    float gm = gmax_s;
    int ln = t >> 5, o = t & 31;
    float acc = 0.f, den = 0.f;
    for (int n0 = beg; n0 < end; n0 += 8) {
        __syncthreads();
        for (int i = t; i < 8 * H; i += 256) {
            int r = i >> 6, c = i & 63;
            int n = n0 + r;
            hs[r][c] = (n < end) ? h[(size_t)n * H + c] : 0.f;
        }
        __syncthreads();
        int n = n0 + ln;
        if (n < end) {
            float wt = __expf(gate[n] - gm);
            float d0 = 0.f;
            #pragma unroll
            for (int i = 0; i < H; i++) d0 += hs[ln][i] * wls[i * OUTD + o];
            acc += wt * d0;
            if (o == 0) den += wt;
        }
    }
    __syncthreads();
    red[t] = acc;
    if (o == 0) den_s[ln] = den;
    __syncthreads();
    for (int sft = 4; sft >= 1; sft >>= 1) {
        if (ln < sft) red[t] += red[t + sft * 32];
        __syncthreads();
    }
    if (t == 0) {
        float dt = 0.f;
        #pragma unroll
        for (int i = 0; i < 8; i++) dt += den_s[i];
        den_tot = dt;
    }
    __syncthreads();
    if (ln == 0) {
        float dt = den_tot;
        out[g * OUTD + o] = (dt > 0.f) ? red[o] / dt + ob[o] : 0.f;
    }
}

extern "C" void kernel_launch(void* const* d_in, const int* in_sizes, int n_in,
                              void* d_out, int out_size, void* d_ws, size_t ws_size,
                              hipStream_t stream)
{
    const int* x        = (const int*)d_in[0];
    const int* ei       = (const int*)d_in[1];
    const int* ea       = (const int*)d_in[2];
    const int* batch    = (const int*)d_in[3];
    const float* node_emb = (const float*)d_in[4];
    const float* edge_emb = (const float*)d_in[5];
    const float* Wq    = (const float*)d_in[6];
    const float* Wk    = (const float*)d_in[7];
    const float* Wv    = (const float*)d_in[8];
    const float* We    = (const float*)d_in[9];
    const float* Wskip = (const float*)d_in[10];
    const float* bq    = (const float*)d_in[11];
    const float* bk    = (const float*)d_in[12];
    const float* bv    = (const float*)d_in[13];
    const float* bskip = (const float*)d_in[14];
    const float* gate_W = (const float*)d_in[15];
    const float* gate_b = (const float*)d_in[16];
    const float* out_W  = (const float*)d_in[17];
    const float* out_b  = (const float*)d_in[18];
    float* out = (float*)d_out;

    const size_t NH = (size_t)N_NODES * H;
    float* ws   = (float*)d_ws;
    float* h    = ws;
    float* q    = h + NH;
    float* kv   = q + NH;          // interleaved k|v per node, 2*NH
    float* s    = kv + 2 * NH;
    float* te   = s + NH;
    float* gate = te + LAYERS * 10 * H;
    int* deg       = (int*)(gate + N_NODES);
    int* row_start = deg + N_NODES;
    int* cursor    = row_start + N_NODES;
    int* packed    = cursor + N_NODES;
    int* gs        = packed + N_EDGES;   // 257 ints
    int* bsum      = gs + NGRAPH + 1;    // 196
    int* boff      = bsum + 256;         // 256

    hipMemsetAsync(deg, 0, N_NODES * sizeof(int), stream);

    k_init_h<<<(N_NODES * H + 255) / 256, 256, 0, stream>>>(x, node_emb, h);
    k_te<<<(LAYERS * 10 * H + 255) / 256, 256, 0, stream>>>(edge_emb, We, te);

    k_hist<<<(N_EDGES + 255) / 256, 256, 0, stream>>>(ei, deg);
    k_scan1<<<SCAN_NB, 256, 0, stream>>>(deg, bsum);
    k_scan2<<<1, 256, 0, stream>>>(bsum, boff);
    k_scan3<<<SCAN_NB, 256, 0, stream>>>(deg, boff, row_start, cursor);
    k_scatter<<<(N_EDGES + 255) / 256, 256, 0, stream>>>(ei, ea, cursor, packed);
    k_gbounds<<<2, 256, 0, stream>>>(batch, gs);

    for (int l = 0; l < LAYERS; l++) {
        k_node_gemm<<<(N_NODES + 63) / 64, 256, 0, stream>>>(
            h,
            Wq + (size_t)l * H * H, Wk + (size_t)l * H * H,
            Wv + (size_t)l * H * H, Wskip + (size_t)l * H * H,
            bq + (size_t)l * H, bk + (size_t)l * H, bv + (size_t)l * H, bskip + (size_t)l * H,
            q, kv, s);
        k_agg<<<(N_NODES + 3) / 4, 256, 0, stream>>>(
            row_start, cursor, packed, q, kv, s, te + (size_t)l * 10 * H, h);
    }

    k_gate<<<(N_NODES + 255) / 256, 256, 0, stream>>>(h, gate_W, gate_b, batch, gate);
    k_readout2<<<NGRAPH, 256, 0, stream>>>(h, out_W, out_b, gate, gs, out);
}

// Round 8
// 665.024 us; speedup vs baseline: 13.5749x; 1.0688x over previous
//
#include <hip/hip_runtime.h>
#include <hip/hip_bf16.h>

#define N_NODES 50000
#define N_EDGES 800000
#define H 64
#define ED 32
#define LAYERS 3
#define NGRAPH 256
#define OUTD 32
#define SCALE 0.125f
#define SCAN_NB ((N_NODES + 255) / 256)   // 196

typedef __attribute__((ext_vector_type(16))) float f16v;

// wave64 sum via DPP (VALU pipe, no LDS): row_shr 1/2/4/8 + row_bcast15/31 -> lane63
__device__ __forceinline__ float wave_sum64(float x) {
    x += __int_as_float(__builtin_amdgcn_update_dpp(0, __float_as_int(x), 0x111, 0xf, 0xf, true));
    x += __int_as_float(__builtin_amdgcn_update_dpp(0, __float_as_int(x), 0x112, 0xf, 0xf, true));
    x += __int_as_float(__builtin_amdgcn_update_dpp(0, __float_as_int(x), 0x114, 0xf, 0xf, true));
    x += __int_as_float(__builtin_amdgcn_update_dpp(0, __float_as_int(x), 0x118, 0xf, 0xf, true));
    x += __int_as_float(__builtin_amdgcn_update_dpp(0, __float_as_int(x), 0x142, 0xa, 0xf, true));
    x += __int_as_float(__builtin_amdgcn_update_dpp(0, __float_as_int(x), 0x143, 0xc, 0xf, true));
    return __int_as_float(__builtin_amdgcn_readlane(__float_as_int(x), 63));
}

// ---------------- init: h = node_emb[x] ----------------
__global__ void k_init_h(const int* __restrict__ x, const float* __restrict__ node_emb,
                         float* __restrict__ h) {
    int i = blockIdx.x * blockDim.x + threadIdx.x;
    if (i >= N_NODES * H) return;
    int n = i >> 6, c = i & 63;
    h[i] = node_emb[x[n] * H + c];
}

// ---------------- te[l][cat][c] ----------------
__global__ void k_te(const float* __restrict__ edge_emb, const float* __restrict__ We,
                     float* __restrict__ te) {
    int i = blockIdx.x * blockDim.x + threadIdx.x;
    if (i >= LAYERS * 10 * H) return;
    int c = i & 63;
    int cat = (i >> 6) % 10;
    int l = i / (10 * H);
    float acc = 0.f;
    for (int d = 0; d < ED; d++)
        acc += edge_emb[cat * ED + d] * We[((size_t)l * ED + d) * H + c];
    te[i] = acc;
}

// ---------------- CSR build ----------------
__global__ void k_hist(const int* __restrict__ ei, int* __restrict__ deg) {
    int e = blockIdx.x * blockDim.x + threadIdx.x;
    if (e >= N_EDGES) return;
    atomicAdd(&deg[ei[N_EDGES + e]], 1);
}

__global__ __launch_bounds__(256) void k_scan1(const int* __restrict__ deg, int* __restrict__ bsum) {
    __shared__ int red[256];
    int t = threadIdx.x;
    int i = blockIdx.x * 256 + t;
    red[t] = (i < N_NODES) ? deg[i] : 0;
    __syncthreads();
    for (int s = 128; s > 0; s >>= 1) {
        if (t < s) red[t] += red[t + s];
        __syncthreads();
    }
    if (t == 0) bsum[blockIdx.x] = red[0];
}

__global__ __launch_bounds__(256) void k_scan2(const int* __restrict__ bsum, int* __restrict__ boff) {
    __shared__ int part[256];
    int t = threadIdx.x;
    part[t] = (t < SCAN_NB) ? bsum[t] : 0;
    __syncthreads();
    for (int off = 1; off < 256; off <<= 1) {
        int add = (t >= off) ? part[t - off] : 0;
        __syncthreads();
        part[t] += add;
        __syncthreads();
    }
    boff[t] = (t == 0) ? 0 : part[t - 1];
}

__global__ __launch_bounds__(256) void k_scan3(const int* __restrict__ deg, const int* __restrict__ boff,
                                               int* __restrict__ row_start, int* __restrict__ cursor) {
    __shared__ int part[256];
    int t = threadIdx.x;
    int i = blockIdx.x * 256 + t;
    int v = (i < N_NODES) ? deg[i] : 0;
    part[t] = v;
    __syncthreads();
    for (int off = 1; off < 256; off <<= 1) {
        int add = (t >= off) ? part[t - off] : 0;
        __syncthreads();
        part[t] += add;
        __syncthreads();
    }
    if (i < N_NODES) {
        int excl = part[t] - v + boff[blockIdx.x];
        row_start[i] = excl;
        cursor[i] = excl;
    }
}

__global__ void k_scatter(const int* __restrict__ ei, const int* __restrict__ ea,
                          int* __restrict__ cursor, int* __restrict__ packed) {
    int e = blockIdx.x * blockDim.x + threadIdx.x;
    if (e >= N_EDGES) return;
    int src = ei[e], dst = ei[N_EDGES + e], cat = ea[e];
    int pos = atomicAdd(&cursor[dst], 1);
    packed[pos] = src | (cat << 16);
}

// ---------------- graph bounds ----------------
__global__ void k_gbounds(const int* __restrict__ batch, int* __restrict__ gs) {
    int g = blockIdx.x * blockDim.x + threadIdx.x;
    if (g > NGRAPH) return;
    int lo = 0, hi = N_NODES;
    while (lo < hi) {
        int mid = (lo + hi) >> 1;
        if (batch[mid] < g) lo = mid + 1; else hi = mid;
    }
    gs[g] = lo;
}

// ---------------- node GEMM: wave = matrix, lane = col, weights in VGPRs ----------------
// h row broadcast via s_load into SGPRs -> inner loop is pure v_fmac (1 VALU op/output)
__global__ __launch_bounds__(256) void k_node_gemm(
    const float* __restrict__ h,
    const float* __restrict__ Wq, const float* __restrict__ Wk,
    const float* __restrict__ Wv, const float* __restrict__ Wsk,
    const float* __restrict__ bq, const float* __restrict__ bk,
    const float* __restrict__ bv, const float* __restrict__ bsk,
    float* __restrict__ q, float* __restrict__ kv, float* __restrict__ s)
{
    int wvi = threadIdx.x >> 6, lane = threadIdx.x & 63;
    const float* Wm = (wvi == 0) ? Wq : (wvi == 1) ? Wk : (wvi == 2) ? Wv : Wsk;
    const float* bm = (wvi == 0) ? bq : (wvi == 1) ? bk : (wvi == 2) ? bv : bsk;
    float wcol[64];
    #pragma unroll 16
    for (int kk = 0; kk < 64; kk++) wcol[kk] = Wm[kk * H + lane];
    float bias = bm[lane];
    int base = blockIdx.x * 64;
    int nEnd = min(base + 64, N_NODES);
    for (int n = base; n < nEnd; n++) {
        const float* hrow = h + (size_t)n * H;
        f16v h0, h1, h2, h3;
        asm volatile(
            "s_load_dwordx16 %0, %4, 0x0\n\t"
            "s_load_dwordx16 %1, %4, 0x40\n\t"
            "s_load_dwordx16 %2, %4, 0x80\n\t"
            "s_load_dwordx16 %3, %4, 0xc0\n\t"
            "s_waitcnt lgkmcnt(0)"
            : "=s"(h0), "=s"(h1), "=s"(h2), "=s"(h3)
            : "s"(hrow));
        float acc = bias;
        #pragma unroll
        for (int i = 0; i < 16; i++) acc = fmaf(h0[i], wcol[i], acc);
        #pragma unroll
        for (int i = 0; i < 16; i++) acc = fmaf(h1[i], wcol[16 + i], acc);
        #pragma unroll
        for (int i = 0; i < 16; i++) acc = fmaf(h2[i], wcol[32 + i], acc);
        #pragma unroll
        for (int i = 0; i < 16; i++) acc = fmaf(h3[i], wcol[48 + i], acc);
        if (wvi == 0)      q[(size_t)n * H + lane] = acc;
        else if (wvi == 3) s[(size_t)n * H + lane] = acc;
        else               kv[(size_t)n * 2 * H + (size_t)(wvi - 1) * H + lane] = acc;
    }
}

// ---------------- fused gather: online softmax, DPP reduce ----------------
__global__ __launch_bounds__(256) void k_agg(
    const int* __restrict__ row_start, const int* __restrict__ row_end,
    const int* __restrict__ packed,
    const float* __restrict__ q, const float* __restrict__ kv,
    const float* __restrict__ s,
    const float* __restrict__ te, float* __restrict__ h)
{
    __shared__ float tel[10 * 64];
    for (int i = threadIdx.x; i < 10 * 64; i += 256) tel[i] = te[i];
    __syncthreads();
    int wave = threadIdx.x >> 6;
    int lane = threadIdx.x & 63;
    int dst = blockIdx.x * 4 + wave;
    if (dst >= N_NODES) return;
    int beg = row_start[dst], end = row_end[dst];
    float qv = q[(size_t)dst * H + lane];
    float m = -INFINITY, l = 0.f, acc = 0.f;
    for (int p0 = beg; p0 < end; p0 += 64) {
        int pk = (p0 + lane < end) ? packed[p0 + lane] : 0;
        int cnt = min(64, end - p0);
        for (int i = 0; i < cnt; i++) {
            int pkt = __builtin_amdgcn_readlane(pk, i);
            int src = pkt & 0xFFFF;
            int cat = pkt >> 16;
            float t = tel[cat * 64 + lane];
            const float* kvp = kv + (size_t)src * 2 * H;
            float kvv = kvp[lane] + t;
            float vv  = kvp[H + lane] + t;
            float a = wave_sum64(qv * kvv) * SCALE;
            float mn = fmaxf(m, a);
            float corr = __expf(m - mn);
            float w = __expf(a - mn);
            acc = acc * corr + w * vv;
            l = l * corr + w;
            m = mn;
        }
    }
    float outv = (l > 0.f) ? acc / l : 0.f;
    float r = outv + s[(size_t)dst * H + lane];
    h[(size_t)dst * H + lane] = fmaxf(r, 0.f);
}

// ---------------- readout gate ----------------
__global__ void k_gate(const float* __restrict__ h, const float* __restrict__ gW,
                       const float* __restrict__ gb, const int* __restrict__ batch,
                       float* __restrict__ gate)
{
    int n = blockIdx.x * blockDim.x + threadIdx.x;
    if (n >= N_NODES) return;
    float acc = gb[0];
    const float* hp = h + (size_t)n * H;
    #pragma unroll
    for (int i = 0; i < H; i++) acc += hp[i] * gW[i];
    gate[n] = acc;
}

// ---------------- fused per-graph readout ----------------
__global__ __launch_bounds__(256) void k_readout2(
    const float* __restrict__ h, const float* __restrict__ oW,
    const float* __restrict__ ob, const float* __restrict__ gate,
    const int* __restrict__ gs, float* __restrict__ out)
{
    __shared__ float wls[H * OUTD];
    __shared__ float hs[8][H + 1];
    __shared__ float red[256];
    __shared__ float den_s[8];
    __shared__ float gmax_s, den_tot;
    int t = threadIdx.x;
    int g = blockIdx.x;
    for (int i = t; i < H * OUTD; i += 256) wls[i] = oW[i];
    int beg = gs[g], end = gs[g + 1];
    float mx = -INFINITY;
    for (int n = beg + t; n < end; n += 256) mx = fmaxf(mx, gate[n]);
    red[t] = mx;
    __syncthreads();
    for (int sft = 128; sft > 0; sft >>= 1) {
        if (t < sft) red[t] = fmaxf(red[t], red[t + sft]);
        __syncthreads();
    }
    if (t == 0) gmax_s = red[0];
    __syncthreads();
    float gm = gmax_s;
    int ln = t >> 5, o = t & 31;
    float acc = 0.f, den = 0.f;
    for (int n0 = beg; n0 < end; n0 += 8) {
        __syncthreads();
        for (int i = t; i < 8 * H; i += 256) {
            int r = i >> 6, c = i & 63;
            int n = n0 + r;
            hs[r][c] = (n < end) ? h[(size_t)n * H + c] : 0.f;
        }
        __syncthreads();
        int n = n0 + ln;
        if (n < end) {
            float wt = __expf(gate[n] - gm);
            float d0 = 0.f;
            #pragma unroll
            for (int i = 0; i < H; i++) d0 += hs[ln][i] * wls[i * OUTD + o];
            acc += wt * d0;
            if (o == 0) den += wt;
        }
    }
    __syncthreads();
    red[t] = acc;
    if (o == 0) den_s[ln] = den;
    __syncthreads();
    for (int sft = 4; sft >= 1; sft >>= 1) {
        if (ln < sft) red[t] += red[t + sft * 32];
        __syncthreads();
    }
    if (t == 0) {
        float dt = 0.f;
        #pragma unroll
        for (int i = 0; i < 8; i++) dt += den_s[i];
        den_tot = dt;
    }
    __syncthreads();
    if (ln == 0) {
        float dt = den_tot;
        out[g * OUTD + o] = (dt > 0.f) ? red[o] / dt + ob[o] : 0.f;
    }
}

extern "C" void kernel_launch(void* const* d_in, const int* in_sizes, int n_in,
                              void* d_out, int out_size, void* d_ws, size_t ws_size,
                              hipStream_t stream)
{
    const int* x        = (const int*)d_in[0];
    const int* ei       = (const int*)d_in[1];
    const int* ea       = (const int*)d_in[2];
    const int* batch    = (const int*)d_in[3];
    const float* node_emb = (const float*)d_in[4];
    const float* edge_emb = (const float*)d_in[5];
    const float* Wq    = (const float*)d_in[6];
    const float* Wk    = (const float*)d_in[7];
    const float* Wv    = (const float*)d_in[8];
    const float* We    = (const float*)d_in[9];
    const float* Wskip = (const float*)d_in[10];
    const float* bq    = (const float*)d_in[11];
    const float* bk    = (const float*)d_in[12];
    const float* bv    = (const float*)d_in[13];
    const float* bskip = (const float*)d_in[14];
    const float* gate_W = (const float*)d_in[15];
    const float* gate_b = (const float*)d_in[16];
    const float* out_W  = (const float*)d_in[17];
    const float* out_b  = (const float*)d_in[18];
    float* out = (float*)d_out;

    const size_t NH = (size_t)N_NODES * H;
    float* ws   = (float*)d_ws;
    float* h    = ws;
    float* q    = h + NH;
    float* kv   = q + NH;          // interleaved k|v per node, 2*NH
    float* s    = kv + 2 * NH;
    float* te   = s + NH;
    float* gate = te + LAYERS * 10 * H;
    int* deg       = (int*)(gate + N_NODES);
    int* row_start = deg + N_NODES;
    int* cursor    = row_start + N_NODES;
    int* packed    = cursor + N_NODES;
    int* gs        = packed + N_EDGES;   // 257 ints
    int* bsum      = gs + NGRAPH + 1;    // 196
    int* boff      = bsum + 256;         // 256

    hipMemsetAsync(deg, 0, N_NODES * sizeof(int), stream);

    k_init_h<<<(N_NODES * H + 255) / 256, 256, 0, stream>>>(x, node_emb, h);
    k_te<<<(LAYERS * 10 * H + 255) / 256, 256, 0, stream>>>(edge_emb, We, te);

    k_hist<<<(N_EDGES + 255) / 256, 256, 0, stream>>>(ei, deg);
    k_scan1<<<SCAN_NB, 256, 0, stream>>>(deg, bsum);
    k_scan2<<<1, 256, 0, stream>>>(bsum, boff);
    k_scan3<<<SCAN_NB, 256, 0, stream>>>(deg, boff, row_start, cursor);
    k_scatter<<<(N_EDGES + 255) / 256, 256, 0, stream>>>(ei, ea, cursor, packed);
    k_gbounds<<<2, 256, 0, stream>>>(batch, gs);

    for (int l = 0; l < LAYERS; l++) {
        k_node_gemm<<<(N_NODES + 63) / 64, 256, 0, stream>>>(
            h,
            Wq + (size_t)l * H * H, Wk + (size_t)l * H * H,
            Wv + (size_t)l * H * H, Wskip + (size_t)l * H * H,
            bq + (size_t)l * H, bk + (size_t)l * H, bv + (size_t)l * H, bskip + (size_t)l * H,
            q, kv, s);
        k_agg<<<(N_NODES + 3) / 4, 256, 0, stream>>>(
            row_start, cursor, packed, q, kv, s, te + (size_t)l * 10 * H, h);
    }

    k_gate<<<(N_NODES + 255) / 256, 256, 0, stream>>>(h, gate_W, gate_b, batch, gate);
    k_readout2<<<NGRAPH, 256, 0, stream>>>(h, out_W, out_b, gate, gs, out);
}

// Round 9
// 613.172 us; speedup vs baseline: 14.7229x; 1.0846x over previous
//
#include <hip/hip_runtime.h>
#include <hip/hip_bf16.h>

#define N_NODES 50000
#define N_EDGES 800000
#define H 64
#define ED 32
#define LAYERS 3
#define NGRAPH 256
#define OUTD 32
#define SCALE 0.125f
#define SCAN_NB ((N_NODES + 255) / 256)   // 196

typedef __attribute__((ext_vector_type(16))) float f16v;

// one DPP-add step applied to 4 independent partials (chains interleave in the pipe)
#define DPP4(ctrl, rm, bm)                                                                  \
    p0 += __int_as_float(__builtin_amdgcn_update_dpp(0, __float_as_int(p0), ctrl, rm, bm, true)); \
    p1 += __int_as_float(__builtin_amdgcn_update_dpp(0, __float_as_int(p1), ctrl, rm, bm, true)); \
    p2 += __int_as_float(__builtin_amdgcn_update_dpp(0, __float_as_int(p2), ctrl, rm, bm, true)); \
    p3 += __int_as_float(__builtin_amdgcn_update_dpp(0, __float_as_int(p3), ctrl, rm, bm, true));

// ---------------- init: h = node_emb[x] ----------------
__global__ void k_init_h(const int* __restrict__ x, const float* __restrict__ node_emb,
                         float* __restrict__ h) {
    int i = blockIdx.x * blockDim.x + threadIdx.x;
    if (i >= N_NODES * H) return;
    int n = i >> 6, c = i & 63;
    h[i] = node_emb[x[n] * H + c];
}

// ---------------- te[l][cat][c] ----------------
__global__ void k_te(const float* __restrict__ edge_emb, const float* __restrict__ We,
                     float* __restrict__ te) {
    int i = blockIdx.x * blockDim.x + threadIdx.x;
    if (i >= LAYERS * 10 * H) return;
    int c = i & 63;
    int cat = (i >> 6) % 10;
    int l = i / (10 * H);
    float acc = 0.f;
    for (int d = 0; d < ED; d++)
        acc += edge_emb[cat * ED + d] * We[((size_t)l * ED + d) * H + c];
    te[i] = acc;
}

// ---------------- CSR build ----------------
__global__ void k_hist(const int* __restrict__ ei, int* __restrict__ deg) {
    int e = blockIdx.x * blockDim.x + threadIdx.x;
    if (e >= N_EDGES) return;
    atomicAdd(&deg[ei[N_EDGES + e]], 1);
}

__global__ __launch_bounds__(256) void k_scan1(const int* __restrict__ deg, int* __restrict__ bsum) {
    __shared__ int red[256];
    int t = threadIdx.x;
    int i = blockIdx.x * 256 + t;
    red[t] = (i < N_NODES) ? deg[i] : 0;
    __syncthreads();
    for (int s = 128; s > 0; s >>= 1) {
        if (t < s) red[t] += red[t + s];
        __syncthreads();
    }
    if (t == 0) bsum[blockIdx.x] = red[0];
}

__global__ __launch_bounds__(256) void k_scan2(const int* __restrict__ bsum, int* __restrict__ boff) {
    __shared__ int part[256];
    int t = threadIdx.x;
    part[t] = (t < SCAN_NB) ? bsum[t] : 0;
    __syncthreads();
    for (int off = 1; off < 256; off <<= 1) {
        int add = (t >= off) ? part[t - off] : 0;
        __syncthreads();
        part[t] += add;
        __syncthreads();
    }
    boff[t] = (t == 0) ? 0 : part[t - 1];
}

__global__ __launch_bounds__(256) void k_scan3(const int* __restrict__ deg, const int* __restrict__ boff,
                                               int* __restrict__ row_start, int* __restrict__ cursor) {
    __shared__ int part[256];
    int t = threadIdx.x;
    int i = blockIdx.x * 256 + t;
    int v = (i < N_NODES) ? deg[i] : 0;
    part[t] = v;
    __syncthreads();
    for (int off = 1; off < 256; off <<= 1) {
        int add = (t >= off) ? part[t - off] : 0;
        __syncthreads();
        part[t] += add;
        __syncthreads();
    }
    if (i < N_NODES) {
        int excl = part[t] - v + boff[blockIdx.x];
        row_start[i] = excl;
        cursor[i] = excl;
    }
}

__global__ void k_scatter(const int* __restrict__ ei, const int* __restrict__ ea,
                          int* __restrict__ cursor, int* __restrict__ packed) {
    int e = blockIdx.x * blockDim.x + threadIdx.x;
    if (e >= N_EDGES) return;
    int src = ei[e], dst = ei[N_EDGES + e], cat = ea[e];
    int pos = atomicAdd(&cursor[dst], 1);
    packed[pos] = src | (cat << 16);
}

// ---------------- graph bounds ----------------
__global__ void k_gbounds(const int* __restrict__ batch, int* __restrict__ gs) {
    int g = blockIdx.x * blockDim.x + threadIdx.x;
    if (g > NGRAPH) return;
    int lo = 0, hi = N_NODES;
    while (lo < hi) {
        int mid = (lo + hi) >> 1;
        if (batch[mid] < g) lo = mid + 1; else hi = mid;
    }
    gs[g] = lo;
}

// ---------------- node GEMM: wave = matrix, lane = col, weights in VGPRs ----------------
// h row via s_load (SGPR broadcast); unified qkvs record [q|k|v|s] 256 floats/node;
// non-temporal stores (don't thrash L2 / evict weights)
__global__ __launch_bounds__(256) void k_node_gemm(
    const float* __restrict__ h,
    const float* __restrict__ Wq, const float* __restrict__ Wk,
    const float* __restrict__ Wv, const float* __restrict__ Wsk,
    const float* __restrict__ bq, const float* __restrict__ bk,
    const float* __restrict__ bv, const float* __restrict__ bsk,
    float* __restrict__ qkvs)
{
    int wvi = threadIdx.x >> 6, lane = threadIdx.x & 63;
    const float* Wm = (wvi == 0) ? Wq : (wvi == 1) ? Wk : (wvi == 2) ? Wv : Wsk;
    const float* bm = (wvi == 0) ? bq : (wvi == 1) ? bk : (wvi == 2) ? bv : bsk;
    float wcol[64];
    #pragma unroll 16
    for (int kk = 0; kk < 64; kk++) wcol[kk] = Wm[kk * H + lane];
    float bias = bm[lane];
    int base = blockIdx.x * 64;
    int nEnd = min(base + 64, N_NODES);
    for (int n = base; n < nEnd; n++) {
        const float* hrow = h + (size_t)n * H;
        f16v h0, h1, h2, h3;
        asm volatile(
            "s_load_dwordx16 %0, %4, 0x0\n\t"
            "s_load_dwordx16 %1, %4, 0x40\n\t"
            "s_load_dwordx16 %2, %4, 0x80\n\t"
            "s_load_dwordx16 %3, %4, 0xc0\n\t"
            "s_waitcnt lgkmcnt(0)"
            : "=s"(h0), "=s"(h1), "=s"(h2), "=s"(h3)
            : "s"(hrow));
        float acc = bias;
        #pragma unroll
        for (int i = 0; i < 16; i++) acc = fmaf(h0[i], wcol[i], acc);
        #pragma unroll
        for (int i = 0; i < 16; i++) acc = fmaf(h1[i], wcol[16 + i], acc);
        #pragma unroll
        for (int i = 0; i < 16; i++) acc = fmaf(h2[i], wcol[32 + i], acc);
        #pragma unroll
        for (int i = 0; i < 16; i++) acc = fmaf(h3[i], wcol[48 + i], acc);
        __builtin_nontemporal_store(acc, qkvs + (size_t)n * 256 + (wvi << 6) + lane);
    }
}

// ---------------- fused gather: 4-edge ILP online softmax ----------------
__global__ __launch_bounds__(256) void k_agg(
    const int* __restrict__ row_start, const int* __restrict__ row_end,
    const int* __restrict__ packed,
    const float* __restrict__ qkvs,
    const float* __restrict__ te, float* __restrict__ h)
{
    __shared__ float tel[10 * 64];
    for (int i = threadIdx.x; i < 10 * 64; i += 256) tel[i] = te[i];
    __syncthreads();
    int wave = threadIdx.x >> 6, lane = threadIdx.x & 63;
    int dst = blockIdx.x * 4 + wave;
    if (dst >= N_NODES) return;
    int beg = row_start[dst], end = row_end[dst];
    const float* drow = qkvs + (size_t)dst * 256;
    float qv = drow[lane];
    float sv = drow[192 + lane];
    float m = -INFINITY, l = 0.f, acc = 0.f;
    for (int pp = beg; pp < end; pp += 64) {
        int pk = (pp + lane < end) ? packed[pp + lane] : 0;
        int cnt = min(64, end - pp);
        for (int i = 0; i < cnt; i += 4) {
            float vv0, vv1, vv2, vv3, p0, p1, p2, p3;
            {
                int pkt = __builtin_amdgcn_readlane(pk, i);
                const float* kr = qkvs + (size_t)(pkt & 0xFFFF) * 256 + 64;
                float t = tel[((pkt >> 16) << 6) + lane];
                float kk = kr[lane] + t; vv0 = kr[64 + lane] + t; p0 = qv * kk;
            }
            {
                int pkt = __builtin_amdgcn_readlane(pk, i + 1);
                const float* kr = qkvs + (size_t)(pkt & 0xFFFF) * 256 + 64;
                float t = tel[((pkt >> 16) << 6) + lane];
                float kk = kr[lane] + t; vv1 = kr[64 + lane] + t; p1 = qv * kk;
            }
            {
                int pkt = __builtin_amdgcn_readlane(pk, i + 2);
                const float* kr = qkvs + (size_t)(pkt & 0xFFFF) * 256 + 64;
                float t = tel[((pkt >> 16) << 6) + lane];
                float kk = kr[lane] + t; vv2 = kr[64 + lane] + t; p2 = qv * kk;
            }
            {
                int pkt = __builtin_amdgcn_readlane(pk, i + 3);
                const float* kr = qkvs + (size_t)(pkt & 0xFFFF) * 256 + 64;
                float t = tel[((pkt >> 16) << 6) + lane];
                float kk = kr[lane] + t; vv3 = kr[64 + lane] + t; p3 = qv * kk;
            }
            DPP4(0x111, 0xf, 0xf) DPP4(0x112, 0xf, 0xf) DPP4(0x114, 0xf, 0xf)
            DPP4(0x118, 0xf, 0xf) DPP4(0x142, 0xa, 0xf) DPP4(0x143, 0xc, 0xf)
            float a0 = __int_as_float(__builtin_amdgcn_readlane(__float_as_int(p0), 63)) * SCALE;
            float a1 = __int_as_float(__builtin_amdgcn_readlane(__float_as_int(p1), 63)) * SCALE;
            float a2 = __int_as_float(__builtin_amdgcn_readlane(__float_as_int(p2), 63)) * SCALE;
            float a3 = __int_as_float(__builtin_amdgcn_readlane(__float_as_int(p3), 63)) * SCALE;
            a1 = (i + 1 < cnt) ? a1 : -INFINITY;
            a2 = (i + 2 < cnt) ? a2 : -INFINITY;
            a3 = (i + 3 < cnt) ? a3 : -INFINITY;
            float amax = fmaxf(fmaxf(a0, a1), fmaxf(a2, a3));
            if (amax <= m) {          // wave-uniform fast path: no rescale needed
                float w0 = __expf(a0 - m), w1 = __expf(a1 - m);
                float w2 = __expf(a2 - m), w3 = __expf(a3 - m);
                acc = fmaf(w0, vv0, acc); acc = fmaf(w1, vv1, acc);
                acc = fmaf(w2, vv2, acc); acc = fmaf(w3, vv3, acc);
                l += (w0 + w1) + (w2 + w3);
            } else {
                float corr = __expf(m - amax);
                float w0 = __expf(a0 - amax), w1 = __expf(a1 - amax);
                float w2 = __expf(a2 - amax), w3 = __expf(a3 - amax);
                acc = acc * corr;
                acc = fmaf(w0, vv0, acc); acc = fmaf(w1, vv1, acc);
                acc = fmaf(w2, vv2, acc); acc = fmaf(w3, vv3, acc);
                l = fmaf(l, corr, (w0 + w1) + (w2 + w3));
                m = amax;
            }
        }
    }
    float outv = (l > 0.f) ? acc / l : 0.f;
    float r = outv + sv;
    h[(size_t)dst * H + lane] = fmaxf(r, 0.f);
}

// ---------------- readout gate ----------------
__global__ void k_gate(const float* __restrict__ h, const float* __restrict__ gW,
                       const float* __restrict__ gb, const int* __restrict__ batch,
                       float* __restrict__ gate)
{
    int n = blockIdx.x * blockDim.x + threadIdx.x;
    if (n >= N_NODES) return;
    float acc = gb[0];
    const float* hp = h + (size_t)n * H;
    #pragma unroll
    for (int i = 0; i < H; i++) acc += hp[i] * gW[i];
    gate[n] = acc;
}

// ---------------- fused per-graph readout ----------------
__global__ __launch_bounds__(256) void k_readout2(
    const float* __restrict__ h, const float* __restrict__ oW,
    const float* __restrict__ ob, const float* __restrict__ gate,
    const int* __restrict__ gs, float* __restrict__ out)
{
    __shared__ float wls[H * OUTD];
    __shared__ float hs[8][H + 1];
    __shared__ float red[256];
    __shared__ float den_s[8];
    __shared__ float gmax_s, den_tot;
    int t = threadIdx.x;
    int g = blockIdx.x;
    for (int i = t; i < H * OUTD; i += 256) wls[i] = oW[i];
    int beg = gs[g], end = gs[g + 1];
    float mx = -INFINITY;
    for (int n = beg + t; n < end; n += 256) mx = fmaxf(mx, gate[n]);
    red[t] = mx;
    __syncthreads();
    for (int sft = 128; sft > 0; sft >>= 1) {
        if (t < sft) red[t] = fmaxf(red[t], red[t + sft]);
        __syncthreads();
    }
    if (t == 0) gmax_s = red[0];
    __syncthreads();
    float gm = gmax_s;
    int ln = t >> 5, o = t & 31;
    float acc = 0.f, den = 0.f;
    for (int n0 = beg; n0 < end; n0 += 8) {
        __syncthreads();
        for (int i = t; i < 8 * H; i += 256) {
            int r = i >> 6, c = i & 63;
            int n = n0 + r;
            hs[r][c] = (n < end) ? h[(size_t)n * H + c] : 0.f;
        }
        __syncthreads();
        int n = n0 + ln;
        if (n < end) {
            float wt = __expf(gate[n] - gm);
            float d0 = 0.f;
            #pragma unroll
            for (int i = 0; i < H; i++) d0 += hs[ln][i] * wls[i * OUTD + o];
            acc += wt * d0;
            if (o == 0) den += wt;
        }
    }
    __syncthreads();
    red[t] = acc;
    if (o == 0) den_s[ln] = den;
    __syncthreads();
    for (int sft = 4; sft >= 1; sft >>= 1) {
        if (ln < sft) red[t] += red[t + sft * 32];
        __syncthreads();
    }
    if (t == 0) {
        float dt = 0.f;
        #pragma unroll
        for (int i = 0; i < 8; i++) dt += den_s[i];
        den_tot = dt;
    }
    __syncthreads();
    if (ln == 0) {
        float dt = den_tot;
        out[g * OUTD + o] = (dt > 0.f) ? red[o] / dt + ob[o] : 0.f;
    }
}

extern "C" void kernel_launch(void* const* d_in, const int* in_sizes, int n_in,
                              void* d_out, int out_size, void* d_ws, size_t ws_size,
                              hipStream_t stream)
{
    const int* x        = (const int*)d_in[0];
    const int* ei       = (const int*)d_in[1];
    const int* ea       = (const int*)d_in[2];
    const int* batch    = (const int*)d_in[3];
    const float* node_emb = (const float*)d_in[4];
    const float* edge_emb = (const float*)d_in[5];
    const float* Wq    = (const float*)d_in[6];
    const float* Wk    = (const float*)d_in[7];
    const float* Wv    = (const float*)d_in[8];
    const float* We    = (const float*)d_in[9];
    const float* Wskip = (const float*)d_in[10];
    const float* bq    = (const float*)d_in[11];
    const float* bk    = (const float*)d_in[12];
    const float* bv    = (const float*)d_in[13];
    const float* bskip = (const float*)d_in[14];
    const float* gate_W = (const float*)d_in[15];
    const float* gate_b = (const float*)d_in[16];
    const float* out_W  = (const float*)d_in[17];
    const float* out_b  = (const float*)d_in[18];
    float* out = (float*)d_out;

    const size_t NH = (size_t)N_NODES * H;
    float* ws   = (float*)d_ws;
    float* h    = ws;
    float* qkvs = h + NH;            // [q|k|v|s] 256 floats per node
    float* te   = qkvs + 4 * NH;
    float* gate = te + LAYERS * 10 * H;
    int* deg       = (int*)(gate + N_NODES);
    int* row_start = deg + N_NODES;
    int* cursor    = row_start + N_NODES;
    int* packed    = cursor + N_NODES;
    int* gs        = packed + N_EDGES;   // 257 ints
    int* bsum      = gs + NGRAPH + 1;    // 196
    int* boff      = bsum + 256;         // 256

    hipMemsetAsync(deg, 0, N_NODES * sizeof(int), stream);

    k_init_h<<<(N_NODES * H + 255) / 256, 256, 0, stream>>>(x, node_emb, h);
    k_te<<<(LAYERS * 10 * H + 255) / 256, 256, 0, stream>>>(edge_emb, We, te);

    k_hist<<<(N_EDGES + 255) / 256, 256, 0, stream>>>(ei, deg);
    k_scan1<<<SCAN_NB, 256, 0, stream>>>(deg, bsum);
    k_scan2<<<1, 256, 0, stream>>>(bsum, boff);
    k_scan3<<<SCAN_NB, 256, 0, stream>>>(deg, boff, row_start, cursor);
    k_scatter<<<(N_EDGES + 255) / 256, 256, 0, stream>>>(ei, ea, cursor, packed);
    k_gbounds<<<2, 256, 0, stream>>>(batch, gs);

    for (int l = 0; l < LAYERS; l++) {
        k_node_gemm<<<(N_NODES + 63) / 64, 256, 0, stream>>>(
            h,
            Wq + (size_t)l * H * H, Wk + (size_t)l * H * H,
            Wv + (size_t)l * H * H, Wskip + (size_t)l * H * H,
            bq + (size_t)l * H, bk + (size_t)l * H, bv + (size_t)l * H, bskip + (size_t)l * H,
            qkvs);
        k_agg<<<(N_NODES + 3) / 4, 256, 0, stream>>>(
            row_start, cursor, packed, qkvs, te + (size_t)l * 10 * H, h);
    }

    k_gate<<<(N_NODES + 255) / 256, 256, 0, stream>>>(h, gate_W, gate_b, batch, gate);
    k_readout2<<<NGRAPH, 256, 0, stream>>>(h, out_W, out_b, gate, gs, out);
}

// Round 10
// 555.649 us; speedup vs baseline: 16.2471x; 1.1035x over previous
//
#include <hip/hip_runtime.h>
#include <hip/hip_bf16.h>

#define N_NODES 50000
#define N_EDGES 800000
#define H 64
#define ED 32
#define LAYERS 3
#define NGRAPH 256
#define OUTD 32
#define SCALE 0.125f
#define SCAN_NB ((N_NODES + 255) / 256)   // 196

typedef __attribute__((ext_vector_type(16))) float f16v;
typedef unsigned short ushort_t;

__device__ __forceinline__ float us2f(ushort_t u) {
    return __uint_as_float(((unsigned)u) << 16);
}
// fp32 -> bf16 round-to-nearest-even
__device__ __forceinline__ ushort_t f2bf(float f) {
    unsigned u = __float_as_uint(f);
    return (ushort_t)((u + 0x7FFFu + ((u >> 16) & 1u)) >> 16);
}

// one DPP-add step applied to 4 independent partials (chains interleave in the pipe)
#define DPP4(ctrl, rm, bm)                                                                  \
    p0 += __int_as_float(__builtin_amdgcn_update_dpp(0, __float_as_int(p0), ctrl, rm, bm, true)); \
    p1 += __int_as_float(__builtin_amdgcn_update_dpp(0, __float_as_int(p1), ctrl, rm, bm, true)); \
    p2 += __int_as_float(__builtin_amdgcn_update_dpp(0, __float_as_int(p2), ctrl, rm, bm, true)); \
    p3 += __int_as_float(__builtin_amdgcn_update_dpp(0, __float_as_int(p3), ctrl, rm, bm, true));

// ---------------- init: h = node_emb[x] ----------------
__global__ void k_init_h(const int* __restrict__ x, const float* __restrict__ node_emb,
                         float* __restrict__ h) {
    int i = blockIdx.x * blockDim.x + threadIdx.x;
    if (i >= N_NODES * H) return;
    int n = i >> 6, c = i & 63;
    h[i] = node_emb[x[n] * H + c];
}

// ---------------- te[l][cat][c] ----------------
__global__ void k_te(const float* __restrict__ edge_emb, const float* __restrict__ We,
                     float* __restrict__ te) {
    int i = blockIdx.x * blockDim.x + threadIdx.x;
    if (i >= LAYERS * 10 * H) return;
    int c = i & 63;
    int cat = (i >> 6) % 10;
    int l = i / (10 * H);
    float acc = 0.f;
    for (int d = 0; d < ED; d++)
        acc += edge_emb[cat * ED + d] * We[((size_t)l * ED + d) * H + c];
    te[i] = acc;
}

// ---------------- CSR build ----------------
__global__ void k_hist(const int* __restrict__ ei, int* __restrict__ deg) {
    int e = blockIdx.x * blockDim.x + threadIdx.x;
    if (e >= N_EDGES) return;
    atomicAdd(&deg[ei[N_EDGES + e]], 1);
}

__global__ __launch_bounds__(256) void k_scan1(const int* __restrict__ deg, int* __restrict__ bsum) {
    __shared__ int red[256];
    int t = threadIdx.x;
    int i = blockIdx.x * 256 + t;
    red[t] = (i < N_NODES) ? deg[i] : 0;
    __syncthreads();
    for (int s = 128; s > 0; s >>= 1) {
        if (t < s) red[t] += red[t + s];
        __syncthreads();
    }
    if (t == 0) bsum[blockIdx.x] = red[0];
}

__global__ __launch_bounds__(256) void k_scan2(const int* __restrict__ bsum, int* __restrict__ boff) {
    __shared__ int part[256];
    int t = threadIdx.x;
    part[t] = (t < SCAN_NB) ? bsum[t] : 0;
    __syncthreads();
    for (int off = 1; off < 256; off <<= 1) {
        int add = (t >= off) ? part[t - off] : 0;
        __syncthreads();
        part[t] += add;
        __syncthreads();
    }
    boff[t] = (t == 0) ? 0 : part[t - 1];
}

__global__ __launch_bounds__(256) void k_scan3(const int* __restrict__ deg, const int* __restrict__ boff,
                                               int* __restrict__ row_start, int* __restrict__ cursor) {
    __shared__ int part[256];
    int t = threadIdx.x;
    int i = blockIdx.x * 256 + t;
    int v = (i < N_NODES) ? deg[i] : 0;
    part[t] = v;
    __syncthreads();
    for (int off = 1; off < 256; off <<= 1) {
        int add = (t >= off) ? part[t - off] : 0;
        __syncthreads();
        part[t] += add;
        __syncthreads();
    }
    if (i < N_NODES) {
        int excl = part[t] - v + boff[blockIdx.x];
        row_start[i] = excl;
        cursor[i] = excl;
    }
}

__global__ void k_scatter(const int* __restrict__ ei, const int* __restrict__ ea,
                          int* __restrict__ cursor, int* __restrict__ packed) {
    int e = blockIdx.x * blockDim.x + threadIdx.x;
    if (e >= N_EDGES) return;
    int src = ei[e], dst = ei[N_EDGES + e], cat = ea[e];
    int pos = atomicAdd(&cursor[dst], 1);
    packed[pos] = src | (cat << 16);
}

// ---------------- graph bounds ----------------
__global__ void k_gbounds(const int* __restrict__ batch, int* __restrict__ gs) {
    int g = blockIdx.x * blockDim.x + threadIdx.x;
    if (g > NGRAPH) return;
    int lo = 0, hi = N_NODES;
    while (lo < hi) {
        int mid = (lo + hi) >> 1;
        if (batch[mid] < g) lo = mid + 1; else hi = mid;
    }
    gs[g] = lo;
}

// ---------------- node GEMM: wave = matrix, lane = col ----------------
// weight column in 4 explicit 16-wide vector registers (NO scratch spill);
// h row via s_load SGPR broadcast; q,s -> fp32 qs[]; k,v -> bf16 kvh[]
__global__ __launch_bounds__(256, 1) void k_node_gemm(
    const float* __restrict__ h,
    const float* __restrict__ Wq, const float* __restrict__ Wk,
    const float* __restrict__ Wv, const float* __restrict__ Wsk,
    const float* __restrict__ bq, const float* __restrict__ bk,
    const float* __restrict__ bv, const float* __restrict__ bsk,
    float* __restrict__ qs, ushort_t* __restrict__ kvh)
{
    int wvi = threadIdx.x >> 6, lane = threadIdx.x & 63;
    const float* Wm = (wvi == 0) ? Wq : (wvi == 1) ? Wk : (wvi == 2) ? Wv : Wsk;
    const float* bm = (wvi == 0) ? bq : (wvi == 1) ? bk : (wvi == 2) ? bv : bsk;
    f16v w0, w1, w2, w3;
    #pragma unroll
    for (int i = 0; i < 16; i++) w0[i] = Wm[i * H + lane];
    #pragma unroll
    for (int i = 0; i < 16; i++) w1[i] = Wm[(16 + i) * H + lane];
    #pragma unroll
    for (int i = 0; i < 16; i++) w2[i] = Wm[(32 + i) * H + lane];
    #pragma unroll
    for (int i = 0; i < 16; i++) w3[i] = Wm[(48 + i) * H + lane];
    float bias = bm[lane];
    int base = blockIdx.x * 64;
    int nEnd = min(base + 64, N_NODES);
    for (int n = base; n < nEnd; n++) {
        const float* hrow = h + (size_t)n * H;
        f16v h0, h1, h2, h3;
        asm volatile(
            "s_load_dwordx16 %0, %4, 0x0\n\t"
            "s_load_dwordx16 %1, %4, 0x40\n\t"
            "s_load_dwordx16 %2, %4, 0x80\n\t"
            "s_load_dwordx16 %3, %4, 0xc0\n\t"
            "s_waitcnt lgkmcnt(0)"
            : "=s"(h0), "=s"(h1), "=s"(h2), "=s"(h3)
            : "s"(hrow));
        float acc = bias;
        #pragma unroll
        for (int i = 0; i < 16; i++) acc = fmaf(h0[i], w0[i], acc);
        #pragma unroll
        for (int i = 0; i < 16; i++) acc = fmaf(h1[i], w1[i], acc);
        #pragma unroll
        for (int i = 0; i < 16; i++) acc = fmaf(h2[i], w2[i], acc);
        #pragma unroll
        for (int i = 0; i < 16; i++) acc = fmaf(h3[i], w3[i], acc);
        if (wvi == 0)      qs[(size_t)n * 128 + lane] = acc;
        else if (wvi == 3) qs[(size_t)n * 128 + 64 + lane] = acc;
        else if (wvi == 1) kvh[(size_t)n * 128 + lane] = f2bf(acc);
        else               kvh[(size_t)n * 128 + 64 + lane] = f2bf(acc);
    }
}

// ---------------- fused gather: 4-edge ILP online softmax, bf16 k/v ----------------
__global__ __launch_bounds__(256) void k_agg(
    const int* __restrict__ row_start, const int* __restrict__ row_end,
    const int* __restrict__ packed,
    const float* __restrict__ qs, const ushort_t* __restrict__ kvh,
    const float* __restrict__ te, float* __restrict__ h)
{
    __shared__ float tel[10 * 64];
    for (int i = threadIdx.x; i < 10 * 64; i += 256) tel[i] = te[i];
    __syncthreads();
    int wave = threadIdx.x >> 6, lane = threadIdx.x & 63;
    int dst = blockIdx.x * 4 + wave;
    if (dst >= N_NODES) return;
    int beg = row_start[dst], end = row_end[dst];
    float qv = qs[(size_t)dst * 128 + lane];
    float sv = qs[(size_t)dst * 128 + 64 + lane];
    float m = -INFINITY, l = 0.f, acc = 0.f;
    for (int pp = beg; pp < end; pp += 64) {
        int pk = (pp + lane < end) ? packed[pp + lane] : 0;
        int cnt = min(64, end - pp);
        for (int i = 0; i < cnt; i += 4) {
            float vv0, vv1, vv2, vv3, p0, p1, p2, p3;
            {
                int pkt = __builtin_amdgcn_readlane(pk, i);
                const ushort_t* kr = kvh + (((size_t)(pkt & 0xFFFF)) << 7);
                float t = tel[((pkt >> 16) << 6) + lane];
                float kk = us2f(kr[lane]) + t; vv0 = us2f(kr[64 + lane]) + t; p0 = qv * kk;
            }
            {
                int pkt = __builtin_amdgcn_readlane(pk, i + 1);
                const ushort_t* kr = kvh + (((size_t)(pkt & 0xFFFF)) << 7);
                float t = tel[((pkt >> 16) << 6) + lane];
                float kk = us2f(kr[lane]) + t; vv1 = us2f(kr[64 + lane]) + t; p1 = qv * kk;
            }
            {
                int pkt = __builtin_amdgcn_readlane(pk, i + 2);
                const ushort_t* kr = kvh + (((size_t)(pkt & 0xFFFF)) << 7);
                float t = tel[((pkt >> 16) << 6) + lane];
                float kk = us2f(kr[lane]) + t; vv2 = us2f(kr[64 + lane]) + t; p2 = qv * kk;
            }
            {
                int pkt = __builtin_amdgcn_readlane(pk, i + 3);
                const ushort_t* kr = kvh + (((size_t)(pkt & 0xFFFF)) << 7);
                float t = tel[((pkt >> 16) << 6) + lane];
                float kk = us2f(kr[lane]) + t; vv3 = us2f(kr[64 + lane]) + t; p3 = qv * kk;
            }
            DPP4(0x111, 0xf, 0xf) DPP4(0x112, 0xf, 0xf) DPP4(0x114, 0xf, 0xf)
            DPP4(0x118, 0xf, 0xf) DPP4(0x142, 0xa, 0xf) DPP4(0x143, 0xc, 0xf)
            float a0 = __int_as_float(__builtin_amdgcn_readlane(__float_as_int(p0), 63)) * SCALE;
            float a1 = __int_as_float(__builtin_amdgcn_readlane(__float_as_int(p1), 63)) * SCALE;
            float a2 = __int_as_float(__builtin_amdgcn_readlane(__float_as_int(p2), 63)) * SCALE;
            float a3 = __int_as_float(__builtin_amdgcn_readlane(__float_as_int(p3), 63)) * SCALE;
            a1 = (i + 1 < cnt) ? a1 : -INFINITY;
            a2 = (i + 2 < cnt) ? a2 : -INFINITY;
            a3 = (i + 3 < cnt) ? a3 : -INFINITY;
            float amax = fmaxf(fmaxf(a0, a1), fmaxf(a2, a3));
            if (amax <= m) {          // wave-uniform fast path: no rescale needed
                float w0 = __expf(a0 - m), w1 = __expf(a1 - m);
                float w2 = __expf(a2 - m), w3 = __expf(a3 - m);
                acc = fmaf(w0, vv0, acc); acc = fmaf(w1, vv1, acc);
                acc = fmaf(w2, vv2, acc); acc = fmaf(w3, vv3, acc);
                l += (w0 + w1) + (w2 + w3);
            } else {
                float corr = __expf(m - amax);
                float w0 = __expf(a0 - amax), w1 = __expf(a1 - amax);
                float w2 = __expf(a2 - amax), w3 = __expf(a3 - amax);
                acc = acc * corr;
                acc = fmaf(w0, vv0, acc); acc = fmaf(w1, vv1, acc);
                acc = fmaf(w2, vv2, acc); acc = fmaf(w3, vv3, acc);
                l = fmaf(l, corr, (w0 + w1) + (w2 + w3));
                m = amax;
            }
        }
    }
    float outv = (l > 0.f) ? acc / l : 0.f;
    float r = outv + sv;
    h[(size_t)dst * H + lane] = fmaxf(r, 0.f);
}

// ---------------- readout gate ----------------
__global__ void k_gate(const float* __restrict__ h, const float* __restrict__ gW,
                       const float* __restrict__ gb, const int* __restrict__ batch,
                       float* __restrict__ gate)
{
    int n = blockIdx.x * blockDim.x + threadIdx.x;
    if (n >= N_NODES) return;
    float acc = gb[0];
    const float* hp = h + (size_t)n * H;
    #pragma unroll
    for (int i = 0; i < H; i++) acc += hp[i] * gW[i];
    gate[n] = acc;
}

// ---------------- fused per-graph readout ----------------
__global__ __launch_bounds__(256) void k_readout2(
    const float* __restrict__ h, const float* __restrict__ oW,
    const float* __restrict__ ob, const float* __restrict__ gate,
    const int* __restrict__ gs, float* __restrict__ out)
{
    __shared__ float wls[H * OUTD];
    __shared__ float hs[8][H + 1];
    __shared__ float red[256];
    __shared__ float den_s[8];
    __shared__ float gmax_s, den_tot;
    int t = threadIdx.x;
    int g = blockIdx.x;
    for (int i = t; i < H * OUTD; i += 256) wls[i] = oW[i];
    int beg = gs[g], end = gs[g + 1];
    float mx = -INFINITY;
    for (int n = beg + t; n < end; n += 256) mx = fmaxf(mx, gate[n]);
    red[t] = mx;
    __syncthreads();
    for (int sft = 128; sft > 0; sft >>= 1) {
        if (t < sft) red[t] = fmaxf(red[t], red[t + sft]);
        __syncthreads();
    }
    if (t == 0) gmax_s = red[0];
    __syncthreads();
    float gm = gmax_s;
    int ln = t >> 5, o = t & 31;
    float acc = 0.f, den = 0.f;
    for (int n0 = beg; n0 < end; n0 += 8) {
        __syncthreads();
        for (int i = t; i < 8 * H; i += 256) {
            int r = i >> 6, c = i & 63;
            int n = n0 + r;
            hs[r][c] = (n < end) ? h[(size_t)n * H + c] : 0.f;
        }
        __syncthreads();
        int n = n0 + ln;
        if (n < end) {
            float wt = __expf(gate[n] - gm);
            float d0 = 0.f;
            #pragma unroll
            for (int i = 0; i < H; i++) d0 += hs[ln][i] * wls[i * OUTD + o];
            acc += wt * d0;
            if (o == 0) den += wt;
        }
    }
    __syncthreads();
    red[t] = acc;
    if (o == 0) den_s[ln] = den;
    __syncthreads();
    for (int sft = 4; sft >= 1; sft >>= 1) {
        if (ln < sft) red[t] += red[t + sft * 32];
        __syncthreads();
    }
    if (t == 0) {
        float dt = 0.f;
        #pragma unroll
        for (int i = 0; i < 8; i++) dt += den_s[i];
        den_tot = dt;
    }
    __syncthreads();
    if (ln == 0) {
        float dt = den_tot;
        out[g * OUTD + o] = (dt > 0.f) ? red[o] / dt + ob[o] : 0.f;
    }
}

extern "C" void kernel_launch(void* const* d_in, const int* in_sizes, int n_in,
                              void* d_out, int out_size, void* d_ws, size_t ws_size,
                              hipStream_t stream)
{
    const int* x        = (const int*)d_in[0];
    const int* ei       = (const int*)d_in[1];
    const int* ea       = (const int*)d_in[2];
    const int* batch    = (const int*)d_in[3];
    const float* node_emb = (const float*)d_in[4];
    const float* edge_emb = (const float*)d_in[5];
    const float* Wq    = (const float*)d_in[6];
    const float* Wk    = (const float*)d_in[7];
    const float* Wv    = (const float*)d_in[8];
    const float* We    = (const float*)d_in[9];
    const float* Wskip = (const float*)d_in[10];
    const float* bq    = (const float*)d_in[11];
    const float* bk    = (const float*)d_in[12];
    const float* bv    = (const float*)d_in[13];
    const float* bskip = (const float*)d_in[14];
    const float* gate_W = (const float*)d_in[15];
    const float* gate_b = (const float*)d_in[16];
    const float* out_W  = (const float*)d_in[17];
    const float* out_b  = (const float*)d_in[18];
    float* out = (float*)d_out;

    const size_t NH = (size_t)N_NODES * H;
    float* ws   = (float*)d_ws;
    float* h    = ws;
    float* qs   = h + NH;                    // fp32 [q|s], 128 floats/node
    ushort_t* kvh = (ushort_t*)(qs + 2 * NH); // bf16 [k|v], 128 ushorts/node (= NH floats of space)
    float* te   = qs + 3 * NH;
    float* gate = te + LAYERS * 10 * H;
    int* deg       = (int*)(gate + N_NODES);
    int* row_start = deg + N_NODES;
    int* cursor    = row_start + N_NODES;
    int* packed    = cursor + N_NODES;
    int* gs        = packed + N_EDGES;   // 257 ints
    int* bsum      = gs + NGRAPH + 1;    // 196
    int* boff      = bsum + 256;         // 256

    hipMemsetAsync(deg, 0, N_NODES * sizeof(int), stream);

    k_init_h<<<(N_NODES * H + 255) / 256, 256, 0, stream>>>(x, node_emb, h);
    k_te<<<(LAYERS * 10 * H + 255) / 256, 256, 0, stream>>>(edge_emb, We, te);

    k_hist<<<(N_EDGES + 255) / 256, 256, 0, stream>>>(ei, deg);
    k_scan1<<<SCAN_NB, 256, 0, stream>>>(deg, bsum);
    k_scan2<<<1, 256, 0, stream>>>(bsum, boff);
    k_scan3<<<SCAN_NB, 256, 0, stream>>>(deg, boff, row_start, cursor);
    k_scatter<<<(N_EDGES + 255) / 256, 256, 0, stream>>>(ei, ea, cursor, packed);
    k_gbounds<<<2, 256, 0, stream>>>(batch, gs);

    for (int l = 0; l < LAYERS; l++) {
        k_node_gemm<<<(N_NODES + 63) / 64, 256, 0, stream>>>(
            h,
            Wq + (size_t)l * H * H, Wk + (size_t)l * H * H,
            Wv + (size_t)l * H * H, Wskip + (size_t)l * H * H,
            bq + (size_t)l * H, bk + (size_t)l * H, bv + (size_t)l * H, bskip + (size_t)l * H,
            qs, kvh);
        k_agg<<<(N_NODES + 3) / 4, 256, 0, stream>>>(
            row_start, cursor, packed, qs, kvh, te + (size_t)l * 10 * H, h);
    }

    k_gate<<<(N_NODES + 255) / 256, 256, 0, stream>>>(h, gate_W, gate_b, batch, gate);
    k_readout2<<<NGRAPH, 256, 0, stream>>>(h, out_W, out_b, gate, gs, out);
}

// Round 12
// 508.530 us; speedup vs baseline: 17.7525x; 1.0927x over previous
//
#include <hip/hip_runtime.h>
#include <hip/hip_bf16.h>

#define N_NODES 50000
#define N_EDGES 800000
#define H 64
#define ED 32
#define LAYERS 3
#define NGRAPH 256
#define OUTD 32
#define SCALE 0.125f
#define SCAN_NB ((N_NODES + 255) / 256)   // 196

// fused front-end block ranges
#define NB_INIT 12500
#define NB_TE   8
#define NB_HIST 3125
#define NB_GB   2
#define NB_FRONT (NB_INIT + NB_TE + NB_HIST + NB_GB)
#define NB_GEMM ((N_NODES + 63) / 64)     // 782

typedef __attribute__((ext_vector_type(16))) float f16v;
typedef unsigned short ushort_t;

// fp32 -> bf16 round-to-nearest-even
__device__ __forceinline__ ushort_t f2bf(float f) {
    unsigned u = __float_as_uint(f);
    return (ushort_t)((u + 0x7FFFu + ((u >> 16) & 1u)) >> 16);
}

// one DPP-add step applied to 4 independent partials (chains interleave in the pipe)
#define DPP4(ctrl, rm, bm)                                                                  \
    p0 += __int_as_float(__builtin_amdgcn_update_dpp(0, __float_as_int(p0), ctrl, rm, bm, true)); \
    p1 += __int_as_float(__builtin_amdgcn_update_dpp(0, __float_as_int(p1), ctrl, rm, bm, true)); \
    p2 += __int_as_float(__builtin_amdgcn_update_dpp(0, __float_as_int(p2), ctrl, rm, bm, true)); \
    p3 += __int_as_float(__builtin_amdgcn_update_dpp(0, __float_as_int(p3), ctrl, rm, bm, true));

// ---------------- fused front end: init_h | te | hist | gbounds ----------------
__global__ __launch_bounds__(256) void k_front(
    const int* __restrict__ x, const float* __restrict__ node_emb, float* __restrict__ h,
    const float* __restrict__ edge_emb, const float* __restrict__ We, float* __restrict__ te,
    const int* __restrict__ ei, int* __restrict__ deg,
    const int* __restrict__ batch, int* __restrict__ gs)
{
    int b = blockIdx.x, t = threadIdx.x;
    if (b < NB_INIT) {
        int i = b * 256 + t;
        int n = i >> 6, c = i & 63;
        h[i] = node_emb[x[n] * H + c];
    } else if (b < NB_INIT + NB_TE) {
        int i = (b - NB_INIT) * 256 + t;
        if (i < LAYERS * 10 * H) {
            int c = i & 63;
            int cat = (i >> 6) % 10;
            int l = i / (10 * H);
            float acc = 0.f;
            for (int d = 0; d < ED; d++)
                acc += edge_emb[cat * ED + d] * We[((size_t)l * ED + d) * H + c];
            te[i] = acc;
        }
    } else if (b < NB_INIT + NB_TE + NB_HIST) {
        int e = (b - NB_INIT - NB_TE) * 256 + t;
        atomicAdd(&deg[ei[N_EDGES + e]], 1);
    } else {
        int g = (b - NB_INIT - NB_TE - NB_HIST) * 256 + t;
        if (g <= NGRAPH) {
            int lo = 0, hi = N_NODES;
            while (lo < hi) {
                int mid = (lo + hi) >> 1;
                if (batch[mid] < g) lo = mid + 1; else hi = mid;
            }
            gs[g] = lo;
        }
    }
}

// ---------------- scans ----------------
__global__ __launch_bounds__(256) void k_scan1(const int* __restrict__ deg, int* __restrict__ bsum) {
    __shared__ int red[256];
    int t = threadIdx.x;
    int i = blockIdx.x * 256 + t;
    red[t] = (i < N_NODES) ? deg[i] : 0;
    __syncthreads();
    for (int s = 128; s > 0; s >>= 1) {
        if (t < s) red[t] += red[t + s];
        __syncthreads();
    }
    if (t == 0) bsum[blockIdx.x] = red[0];
}

__global__ __launch_bounds__(256) void k_scan2(const int* __restrict__ bsum, int* __restrict__ boff) {
    __shared__ int part[256];
    int t = threadIdx.x;
    part[t] = (t < SCAN_NB) ? bsum[t] : 0;
    __syncthreads();
    for (int off = 1; off < 256; off <<= 1) {
        int add = (t >= off) ? part[t - off] : 0;
        __syncthreads();
        part[t] += add;
        __syncthreads();
    }
    boff[t] = (t == 0) ? 0 : part[t - 1];
}

__global__ __launch_bounds__(256) void k_scan3(const int* __restrict__ deg, const int* __restrict__ boff,
                                               int* __restrict__ row_start, int* __restrict__ cursor) {
    __shared__ int part[256];
    int t = threadIdx.x;
    int i = blockIdx.x * 256 + t;
    int v = (i < N_NODES) ? deg[i] : 0;
    part[t] = v;
    __syncthreads();
    for (int off = 1; off < 256; off <<= 1) {
        int add = (t >= off) ? part[t - off] : 0;
        __syncthreads();
        part[t] += add;
        __syncthreads();
    }
    if (i < N_NODES) {
        int excl = part[t] - v + boff[blockIdx.x];
        row_start[i] = excl;
        cursor[i] = excl;
    }
}

// ---------------- gemm body: wave = matrix, lane = col ----------------
// weight column in 4 explicit 16-wide vector regs; h row via s_load SGPR broadcast
// q,s -> qs interleaved (q at 2c, s at 2c+1); k,v -> one uint (k hi16, v lo16)
__device__ __forceinline__ void gemm_body(
    int bid, const float* __restrict__ h,
    const float* __restrict__ Wq, const float* __restrict__ Wk,
    const float* __restrict__ Wv, const float* __restrict__ Wsk,
    const float* __restrict__ bq, const float* __restrict__ bk,
    const float* __restrict__ bv, const float* __restrict__ bsk,
    float* __restrict__ qs, unsigned* __restrict__ kv32)
{
    int wvi = threadIdx.x >> 6, lane = threadIdx.x & 63;
    const float* Wm = (wvi == 0) ? Wq : (wvi == 1) ? Wk : (wvi == 2) ? Wv : Wsk;
    const float* bm = (wvi == 0) ? bq : (wvi == 1) ? bk : (wvi == 2) ? bv : bsk;
    f16v w0, w1, w2, w3;
    #pragma unroll
    for (int i = 0; i < 16; i++) w0[i] = Wm[i * H + lane];
    #pragma unroll
    for (int i = 0; i < 16; i++) w1[i] = Wm[(16 + i) * H + lane];
    #pragma unroll
    for (int i = 0; i < 16; i++) w2[i] = Wm[(32 + i) * H + lane];
    #pragma unroll
    for (int i = 0; i < 16; i++) w3[i] = Wm[(48 + i) * H + lane];
    float bias = bm[lane];
    int base = bid * 64;
    int nEnd = min(base + 64, N_NODES);
    for (int n = base; n < nEnd; n++) {
        const float* hrow = h + (size_t)n * H;
        f16v h0, h1, h2, h3;
        asm volatile(
            "s_load_dwordx16 %0, %4, 0x0\n\t"
            "s_load_dwordx16 %1, %4, 0x40\n\t"
            "s_load_dwordx16 %2, %4, 0x80\n\t"
            "s_load_dwordx16 %3, %4, 0xc0\n\t"
            "s_waitcnt lgkmcnt(0)"
            : "=s"(h0), "=s"(h1), "=s"(h2), "=s"(h3)
            : "s"(hrow));
        float acc = bias;
        #pragma unroll
        for (int i = 0; i < 16; i++) acc = fmaf(h0[i], w0[i], acc);
        #pragma unroll
        for (int i = 0; i < 16; i++) acc = fmaf(h1[i], w1[i], acc);
        #pragma unroll
        for (int i = 0; i < 16; i++) acc = fmaf(h2[i], w2[i], acc);
        #pragma unroll
        for (int i = 0; i < 16; i++) acc = fmaf(h3[i], w3[i], acc);
        if (wvi == 0)      qs[(size_t)n * 128 + 2 * lane] = acc;
        else if (wvi == 3) qs[(size_t)n * 128 + 2 * lane + 1] = acc;
        else if (wvi == 1) ((ushort_t*)kv32)[(((size_t)n << 6) + lane) * 2 + 1] = f2bf(acc);
        else               ((ushort_t*)kv32)[(((size_t)n << 6) + lane) * 2 + 0] = f2bf(acc);
    }
}

// layers 1,2: plain gemm
__global__ __launch_bounds__(256, 1) void k_gemm(
    const float* __restrict__ h,
    const float* __restrict__ Wq, const float* __restrict__ Wk,
    const float* __restrict__ Wv, const float* __restrict__ Wsk,
    const float* __restrict__ bq, const float* __restrict__ bk,
    const float* __restrict__ bv, const float* __restrict__ bsk,
    float* __restrict__ qs, unsigned* __restrict__ kv32)
{
    gemm_body(blockIdx.x, h, Wq, Wk, Wv, Wsk, bq, bk, bv, bsk, qs, kv32);
}

// layer 0: gemm blocks [0,NB_GEMM), scatter blocks [NB_GEMM, NB_GEMM+NB_HIST)
__global__ __launch_bounds__(256, 1) void k_gemm_scatter(
    const float* __restrict__ h,
    const float* __restrict__ Wq, const float* __restrict__ Wk,
    const float* __restrict__ Wv, const float* __restrict__ Wsk,
    const float* __restrict__ bq, const float* __restrict__ bk,
    const float* __restrict__ bv, const float* __restrict__ bsk,
    float* __restrict__ qs, unsigned* __restrict__ kv32,
    const int* __restrict__ ei, const int* __restrict__ ea,
    int* __restrict__ cursor, int* __restrict__ packed)
{
    int b = blockIdx.x;
    if (b < NB_GEMM) {
        gemm_body(b, h, Wq, Wk, Wv, Wsk, bq, bk, bv, bsk, qs, kv32);
    } else {
        int e = (b - NB_GEMM) * 256 + threadIdx.x;
        int src = ei[e], dst = ei[N_EDGES + e], cat = ea[e];
        int pos = atomicAdd(&cursor[dst], 1);
        packed[pos] = src | (cat << 16);
    }
}

// ---------------- fused gather: 4-edge ILP online softmax, packed bf16 k|v ----------------
__global__ __launch_bounds__(256) void k_agg(
    const int* __restrict__ row_start, const int* __restrict__ row_end,
    const int* __restrict__ packed,
    const float* __restrict__ qs, const unsigned* __restrict__ kv32,
    const float* __restrict__ te, float* __restrict__ h)
{
    __shared__ float tel[10 * 64];
    for (int i = threadIdx.x; i < 10 * 64; i += 256) tel[i] = te[i];
    __syncthreads();
    int wave = threadIdx.x >> 6, lane = threadIdx.x & 63;
    int dst = blockIdx.x * 4 + wave;
    if (dst >= N_NODES) return;
    int beg = row_start[dst], end = row_end[dst];
    float2 qsl = *(const float2*)&qs[(size_t)dst * 128 + 2 * lane];
    float qv = qsl.x, sv = qsl.y;
    float m = -INFINITY, l = 0.f, acc = 0.f;
    for (int pp = beg; pp < end; pp += 64) {
        int pk = (pp + lane < end) ? packed[pp + lane] : 0;
        int cnt = min(64, end - pp);
        for (int i = 0; i < cnt; i += 4) {
            float vv0, vv1, vv2, vv3, p0, p1, p2, p3;
            {
                int pkt = __builtin_amdgcn_readlane(pk, i);
                unsigned wrd = kv32[((size_t)(pkt & 0xFFFF) << 6) + lane];
                float t = tel[((pkt >> 16) << 6) + lane];
                p0 = qv * (__uint_as_float(wrd & 0xFFFF0000u) + t);   // key_j = k[src] + te
                vv0 = __uint_as_float(wrd << 16) + t;
            }
            {
                int pkt = __builtin_amdgcn_readlane(pk, i + 1);
                unsigned wrd = kv32[((size_t)(pkt & 0xFFFF) << 6) + lane];
                float t = tel[((pkt >> 16) << 6) + lane];
                p1 = qv * (__uint_as_float(wrd & 0xFFFF0000u) + t);
                vv1 = __uint_as_float(wrd << 16) + t;
            }
            {
                int pkt = __builtin_amdgcn_readlane(pk, i + 2);
                unsigned wrd = kv32[((size_t)(pkt & 0xFFFF) << 6) + lane];
                float t = tel[((pkt >> 16) << 6) + lane];
                p2 = qv * (__uint_as_float(wrd & 0xFFFF0000u) + t);
                vv2 = __uint_as_float(wrd << 16) + t;
            }
            {
                int pkt = __builtin_amdgcn_readlane(pk, i + 3);
                unsigned wrd = kv32[((size_t)(pkt & 0xFFFF) << 6) + lane];
                float t = tel[((pkt >> 16) << 6) + lane];
                p3 = qv * (__uint_as_float(wrd & 0xFFFF0000u) + t);
                vv3 = __uint_as_float(wrd << 16) + t;
            }
            DPP4(0x111, 0xf, 0xf) DPP4(0x112, 0xf, 0xf) DPP4(0x114, 0xf, 0xf)
            DPP4(0x118, 0xf, 0xf) DPP4(0x142, 0xa, 0xf) DPP4(0x143, 0xc, 0xf)
            float a0 = __int_as_float(__builtin_amdgcn_readlane(__float_as_int(p0), 63)) * SCALE;
            float a1 = __int_as_float(__builtin_amdgcn_readlane(__float_as_int(p1), 63)) * SCALE;
            float a2 = __int_as_float(__builtin_amdgcn_readlane(__float_as_int(p2), 63)) * SCALE;
            float a3 = __int_as_float(__builtin_amdgcn_readlane(__float_as_int(p3), 63)) * SCALE;
            a1 = (i + 1 < cnt) ? a1 : -INFINITY;
            a2 = (i + 2 < cnt) ? a2 : -INFINITY;
            a3 = (i + 3 < cnt) ? a3 : -INFINITY;
            float amax = fmaxf(fmaxf(a0, a1), fmaxf(a2, a3));
            if (amax <= m) {          // wave-uniform fast path: no rescale needed
                float w0 = __expf(a0 - m), w1 = __expf(a1 - m);
                float w2 = __expf(a2 - m), w3 = __expf(a3 - m);
                acc = fmaf(w0, vv0, acc); acc = fmaf(w1, vv1, acc);
                acc = fmaf(w2, vv2, acc); acc = fmaf(w3, vv3, acc);
                l += (w0 + w1) + (w2 + w3);
            } else {
                float corr = __expf(m - amax);
                float w0 = __expf(a0 - amax), w1 = __expf(a1 - amax);
                float w2 = __expf(a2 - amax), w3 = __expf(a3 - amax);
                acc = acc * corr;
                acc = fmaf(w0, vv0, acc); acc = fmaf(w1, vv1, acc);
                acc = fmaf(w2, vv2, acc); acc = fmaf(w3, vv3, acc);
                l = fmaf(l, corr, (w0 + w1) + (w2 + w3));
                m = amax;
            }
        }
    }
    float outv = (l > 0.f) ? acc / l : 0.f;
    float r = outv + sv;
    h[(size_t)dst * H + lane] = fmaxf(r, 0.f);
}

// ---------------- readout gate ----------------
__global__ void k_gate(const float* __restrict__ h, const float* __restrict__ gW,
                       const float* __restrict__ gb, const int* __restrict__ batch,
                       float* __restrict__ gate)
{
    int n = blockIdx.x * blockDim.x + threadIdx.x;
    if (n >= N_NODES) return;
    float acc = gb[0];
    const float* hp = h + (size_t)n * H;
    #pragma unroll
    for (int i = 0; i < H; i++) acc += hp[i] * gW[i];
    gate[n] = acc;
}

// ---------------- fused per-graph readout ----------------
__global__ __launch_bounds__(256) void k_readout2(
    const float* __restrict__ h, const float* __restrict__ oW,
    const float* __restrict__ ob, const float* __restrict__ gate,
    const int* __restrict__ gs, float* __restrict__ out)
{
    __shared__ float wls[H * OUTD];
    __shared__ float hs[8][H + 1];
    __shared__ float red[256];
    __shared__ float den_s[8];
    __shared__ float gmax_s, den_tot;
    int t = threadIdx.x;
    int g = blockIdx.x;
    for (int i = t; i < H * OUTD; i += 256) wls[i] = oW[i];
    int beg = gs[g], end = gs[g + 1];
    float mx = -INFINITY;
    for (int n = beg + t; n < end; n += 256) mx = fmaxf(mx, gate[n]);
    red[t] = mx;
    __syncthreads();
    for (int sft = 128; sft > 0; sft >>= 1) {
        if (t < sft) red[t] = fmaxf(red[t], red[t + sft]);
        __syncthreads();
    }
    if (t == 0) gmax_s = red[0];
    __syncthreads();
    float gm = gmax_s;
    int ln = t >> 5, o = t & 31;
    float acc = 0.f, den = 0.f;
    for (int n0 = beg; n0 < end; n0 += 8) {
        __syncthreads();
        for (int i = t; i < 8 * H; i += 256) {
            int r = i >> 6, c = i & 63;
            int n = n0 + r;
            hs[r][c] = (n < end) ? h[(size_t)n * H + c] : 0.f;
        }
        __syncthreads();
        int n = n0 + ln;
        if (n < end) {
            float wt = __expf(gate[n] - gm);
            float d0 = 0.f;
            #pragma unroll
            for (int i = 0; i < H; i++) d0 += hs[ln][i] * wls[i * OUTD + o];
            acc += wt * d0;
            if (o == 0) den += wt;
        }
    }
    __syncthreads();
    red[t] = acc;
    if (o == 0) den_s[ln] = den;
    __syncthreads();
    for (int sft = 4; sft >= 1; sft >>= 1) {
        if (ln < sft) red[t] += red[t + sft * 32];
        __syncthreads();
    }
    if (t == 0) {
        float dt = 0.f;
        #pragma unroll
        for (int i = 0; i < 8; i++) dt += den_s[i];
        den_tot = dt;
    }
    __syncthreads();
    if (ln == 0) {
        float dt = den_tot;
        out[g * OUTD + o] = (dt > 0.f) ? red[o] / dt + ob[o] : 0.f;
    }
}

extern "C" void kernel_launch(void* const* d_in, const int* in_sizes, int n_in,
                              void* d_out, int out_size, void* d_ws, size_t ws_size,
                              hipStream_t stream)
{
    const int* x        = (const int*)d_in[0];
    const int* ei       = (const int*)d_in[1];
    const int* ea       = (const int*)d_in[2];
    const int* batch    = (const int*)d_in[3];
    const float* node_emb = (const float*)d_in[4];
    const float* edge_emb = (const float*)d_in[5];
    const float* Wq    = (const float*)d_in[6];
    const float* Wk    = (const float*)d_in[7];
    const float* Wv    = (const float*)d_in[8];
    const float* We    = (const float*)d_in[9];
    const float* Wskip = (const float*)d_in[10];
    const float* bq    = (const float*)d_in[11];
    const float* bk    = (const float*)d_in[12];
    const float* bv    = (const float*)d_in[13];
    const float* bskip = (const float*)d_in[14];
    const float* gate_W = (const float*)d_in[15];
    const float* gate_b = (const float*)d_in[16];
    const float* out_W  = (const float*)d_in[17];
    const float* out_b  = (const float*)d_in[18];
    float* out = (float*)d_out;

    const size_t NH = (size_t)N_NODES * H;
    float* ws   = (float*)d_ws;
    float* h    = ws;
    float* qs   = h + NH;                    // fp32 [q|s] interleaved, 128 floats/node
    unsigned* kv32 = (unsigned*)(qs + 2 * NH); // packed bf16 k|v, 64 uints/node
    float* te   = (float*)(kv32 + NH);
    float* gate = te + LAYERS * 10 * H;
    int* deg       = (int*)(gate + N_NODES);
    int* row_start = deg + N_NODES;
    int* cursor    = row_start + N_NODES;
    int* packed    = cursor + N_NODES;
    int* gs        = packed + N_EDGES;   // 257 ints
    int* bsum      = gs + NGRAPH + 1;    // 196
    int* boff      = bsum + 256;         // 256

    hipMemsetAsync(deg, 0, N_NODES * sizeof(int), stream);

    k_front<<<NB_FRONT, 256, 0, stream>>>(x, node_emb, h, edge_emb, We, te, ei, deg, batch, gs);
    k_scan1<<<SCAN_NB, 256, 0, stream>>>(deg, bsum);
    k_scan2<<<1, 256, 0, stream>>>(bsum, boff);
    k_scan3<<<SCAN_NB, 256, 0, stream>>>(deg, boff, row_start, cursor);

    // layer 0: gemm fused with scatter (independent work, co-scheduled)
    k_gemm_scatter<<<NB_GEMM + NB_HIST, 256, 0, stream>>>(
        h, Wq, Wk, Wv, Wskip, bq, bk, bv, bskip, qs, kv32, ei, ea, cursor, packed);
    k_agg<<<(N_NODES + 3) / 4, 256, 0, stream>>>(
        row_start, cursor, packed, qs, kv32, te, h);

    for (int l = 1; l < LAYERS; l++) {
        k_gemm<<<NB_GEMM, 256, 0, stream>>>(
            h,
            Wq + (size_t)l * H * H, Wk + (size_t)l * H * H,
            Wv + (size_t)l * H * H, Wskip + (size_t)l * H * H,
            bq + (size_t)l * H, bk + (size_t)l * H, bv + (size_t)l * H, bskip + (size_t)l * H,
            qs, kv32);
        k_agg<<<(N_NODES + 3) / 4, 256, 0, stream>>>(
            row_start, cursor, packed, qs, kv32, te + (size_t)l * 10 * H, h);
    }

    k_gate<<<(N_NODES + 255) / 256, 256, 0, stream>>>(h, gate_W, gate_b, batch, gate);
    k_readout2<<<NGRAPH, 256, 0, stream>>>(h, out_W, out_b, gate, gs, out);
}

// Round 13
// 487.495 us; speedup vs baseline: 18.5185x; 1.0431x over previous
//
#include <hip/hip_runtime.h>
#include <hip/hip_bf16.h>

#define N_NODES 50000
#define N_EDGES 800000
#define H 64
#define ED 32
#define LAYERS 3
#define NGRAPH 256
#define OUTD 32
#define SCALE 0.125f
#define SCAN_NB ((N_NODES + 255) / 256)   // 196

// fused front-end block ranges
#define NB_INIT 12500
#define NB_TE   8
#define NB_HIST 3125
#define NB_GB   2
#define NB_FRONT (NB_INIT + NB_TE + NB_HIST + NB_GB)
#define NB_GEMM ((N_NODES + 63) / 64)     // 782

typedef __attribute__((ext_vector_type(16))) float f16v;
typedef unsigned short ushort_t;

// fp32 -> bf16 round-to-nearest-even
__device__ __forceinline__ ushort_t f2bf(float f) {
    unsigned u = __float_as_uint(f);
    return (ushort_t)((u + 0x7FFFu + ((u >> 16) & 1u)) >> 16);
}

// ---------------- fused front end: init_h | te | hist | gbounds ----------------
__global__ __launch_bounds__(256) void k_front(
    const int* __restrict__ x, const float* __restrict__ node_emb, float* __restrict__ h,
    const float* __restrict__ edge_emb, const float* __restrict__ We, float* __restrict__ te,
    const int* __restrict__ ei, int* __restrict__ deg,
    const int* __restrict__ batch, int* __restrict__ gs)
{
    int b = blockIdx.x, t = threadIdx.x;
    if (b < NB_INIT) {
        int i = b * 256 + t;
        int n = i >> 6, c = i & 63;
        h[i] = node_emb[x[n] * H + c];
    } else if (b < NB_INIT + NB_TE) {
        int i = (b - NB_INIT) * 256 + t;
        if (i < LAYERS * 10 * H) {
            int c = i & 63;
            int cat = (i >> 6) % 10;
            int l = i / (10 * H);
            float acc = 0.f;
            for (int d = 0; d < ED; d++)
                acc += edge_emb[cat * ED + d] * We[((size_t)l * ED + d) * H + c];
            te[i] = acc;
        }
    } else if (b < NB_INIT + NB_TE + NB_HIST) {
        int e = (b - NB_INIT - NB_TE) * 256 + t;
        atomicAdd(&deg[ei[N_EDGES + e]], 1);
    } else {
        int g = (b - NB_INIT - NB_TE - NB_HIST) * 256 + t;
        if (g <= NGRAPH) {
            int lo = 0, hi = N_NODES;
            while (lo < hi) {
                int mid = (lo + hi) >> 1;
                if (batch[mid] < g) lo = mid + 1; else hi = mid;
            }
            gs[g] = lo;
        }
    }
}

// ---------------- scans ----------------
__global__ __launch_bounds__(256) void k_scan1(const int* __restrict__ deg, int* __restrict__ bsum) {
    __shared__ int red[256];
    int t = threadIdx.x;
    int i = blockIdx.x * 256 + t;
    red[t] = (i < N_NODES) ? deg[i] : 0;
    __syncthreads();
    for (int s = 128; s > 0; s >>= 1) {
        if (t < s) red[t] += red[t + s];
        __syncthreads();
    }
    if (t == 0) bsum[blockIdx.x] = red[0];
}

// merged scan2+scan3: each block redundantly scans the 196 block sums, then local scan
__global__ __launch_bounds__(256) void k_scan23(const int* __restrict__ deg, const int* __restrict__ bsum,
                                                int* __restrict__ row_start, int* __restrict__ cursor) {
    __shared__ int part[256];
    int t = threadIdx.x;
    // phase 1: inclusive scan of block sums
    part[t] = (t < SCAN_NB) ? bsum[t] : 0;
    __syncthreads();
    for (int off = 1; off < 256; off <<= 1) {
        int add = (t >= off) ? part[t - off] : 0;
        __syncthreads();
        part[t] += add;
        __syncthreads();
    }
    int boff = (blockIdx.x == 0) ? 0 : part[blockIdx.x - 1];
    __syncthreads();
    // phase 2: local scan of this block's deg chunk
    int i = blockIdx.x * 256 + t;
    int v = (i < N_NODES) ? deg[i] : 0;
    part[t] = v;
    __syncthreads();
    for (int off = 1; off < 256; off <<= 1) {
        int add = (t >= off) ? part[t - off] : 0;
        __syncthreads();
        part[t] += add;
        __syncthreads();
    }
    if (i < N_NODES) {
        int excl = part[t] - v + boff;
        row_start[i] = excl;
        cursor[i] = excl;
    }
}

// ---------------- gemm body: wave = matrix, lane = col ----------------
// q -> qs[n][0:64) fp32; s -> qs[n][64:128) fp32; k,v -> one uint (k hi16, v lo16)
__device__ __forceinline__ void gemm_body(
    int bid, const float* __restrict__ h,
    const float* __restrict__ Wq, const float* __restrict__ Wk,
    const float* __restrict__ Wv, const float* __restrict__ Wsk,
    const float* __restrict__ bq, const float* __restrict__ bk,
    const float* __restrict__ bv, const float* __restrict__ bsk,
    float* __restrict__ qs, unsigned* __restrict__ kv32)
{
    int wvi = threadIdx.x >> 6, lane = threadIdx.x & 63;
    const float* Wm = (wvi == 0) ? Wq : (wvi == 1) ? Wk : (wvi == 2) ? Wv : Wsk;
    const float* bm = (wvi == 0) ? bq : (wvi == 1) ? bk : (wvi == 2) ? bv : bsk;
    f16v w0, w1, w2, w3;
    #pragma unroll
    for (int i = 0; i < 16; i++) w0[i] = Wm[i * H + lane];
    #pragma unroll
    for (int i = 0; i < 16; i++) w1[i] = Wm[(16 + i) * H + lane];
    #pragma unroll
    for (int i = 0; i < 16; i++) w2[i] = Wm[(32 + i) * H + lane];
    #pragma unroll
    for (int i = 0; i < 16; i++) w3[i] = Wm[(48 + i) * H + lane];
    float bias = bm[lane];
    int base = bid * 64;
    int nEnd = min(base + 64, N_NODES);
    for (int n = base; n < nEnd; n++) {
        const float* hrow = h + (size_t)n * H;
        f16v h0, h1, h2, h3;
        asm volatile(
            "s_load_dwordx16 %0, %4, 0x0\n\t"
            "s_load_dwordx16 %1, %4, 0x40\n\t"
            "s_load_dwordx16 %2, %4, 0x80\n\t"
            "s_load_dwordx16 %3, %4, 0xc0\n\t"
            "s_waitcnt lgkmcnt(0)"
            : "=s"(h0), "=s"(h1), "=s"(h2), "=s"(h3)
            : "s"(hrow));
        float acc = bias;
        #pragma unroll
        for (int i = 0; i < 16; i++) acc = fmaf(h0[i], w0[i], acc);
        #pragma unroll
        for (int i = 0; i < 16; i++) acc = fmaf(h1[i], w1[i], acc);
        #pragma unroll
        for (int i = 0; i < 16; i++) acc = fmaf(h2[i], w2[i], acc);
        #pragma unroll
        for (int i = 0; i < 16; i++) acc = fmaf(h3[i], w3[i], acc);
        if (wvi == 0)      qs[(size_t)n * 128 + lane] = acc;
        else if (wvi == 3) qs[(size_t)n * 128 + 64 + lane] = acc;
        else if (wvi == 1) ((ushort_t*)kv32)[(((size_t)n << 6) + lane) * 2 + 1] = f2bf(acc);
        else               ((ushort_t*)kv32)[(((size_t)n << 6) + lane) * 2 + 0] = f2bf(acc);
    }
}

// layers 1,2: plain gemm
__global__ __launch_bounds__(256, 1) void k_gemm(
    const float* __restrict__ h,
    const float* __restrict__ Wq, const float* __restrict__ Wk,
    const float* __restrict__ Wv, const float* __restrict__ Wsk,
    const float* __restrict__ bq, const float* __restrict__ bk,
    const float* __restrict__ bv, const float* __restrict__ bsk,
    float* __restrict__ qs, unsigned* __restrict__ kv32)
{
    gemm_body(blockIdx.x, h, Wq, Wk, Wv, Wsk, bq, bk, bv, bsk, qs, kv32);
}

// layer 0: gemm blocks [0,NB_GEMM), scatter blocks [NB_GEMM, NB_GEMM+NB_HIST)
__global__ __launch_bounds__(256, 1) void k_gemm_scatter(
    const float* __restrict__ h,
    const float* __restrict__ Wq, const float* __restrict__ Wk,
    const float* __restrict__ Wv, const float* __restrict__ Wsk,
    const float* __restrict__ bq, const float* __restrict__ bk,
    const float* __restrict__ bv, const float* __restrict__ bsk,
    float* __restrict__ qs, unsigned* __restrict__ kv32,
    const int* __restrict__ ei, const int* __restrict__ ea,
    int* __restrict__ cursor, int* __restrict__ packed)
{
    int b = blockIdx.x;
    if (b < NB_GEMM) {
        gemm_body(b, h, Wq, Wk, Wv, Wsk, bq, bk, bv, bsk, qs, kv32);
    } else {
        int e = (b - NB_GEMM) * 256 + threadIdx.x;
        int src = ei[e], dst = ei[N_EDGES + e], cat = ea[e];
        int pos = atomicAdd(&cursor[dst], 1);
        packed[pos] = src | (cat << 16);
    }
}

// ---------------- fused gather v2: 4x16 lane-split, one edge per 16-lane group --------
// lane = g*16 + i16; each lane holds 4 channels (uint4 kv row load, float4 q).
// per-group online softmax (m,l,acc), flash-style merge across groups at the end.
// optional fused gate computation (layer 2).
__global__ __launch_bounds__(256) void k_agg(
    const int* __restrict__ row_start, const int* __restrict__ row_end,
    const int* __restrict__ packed,
    const float* __restrict__ qs, const unsigned* __restrict__ kv32,
    const float* __restrict__ te, float* __restrict__ h,
    const float* __restrict__ gW, const float* __restrict__ gb, float* __restrict__ gate)
{
    __shared__ float tel[10 * 64];
    for (int i = threadIdx.x; i < 10 * 64; i += 256) tel[i] = te[i];
    __syncthreads();
    int wave = threadIdx.x >> 6, lane = threadIdx.x & 63;
    int g = lane >> 4, i16 = lane & 15;
    int dst = blockIdx.x * 4 + wave;
    if (dst >= N_NODES) return;
    int beg = row_start[dst], end = row_end[dst];
    float4 q4 = *(const float4*)(qs + (size_t)dst * 128 + (i16 << 2));
    float m = -1e30f, l = 0.f;
    float4 acc = {0.f, 0.f, 0.f, 0.f};
    for (int e = beg + g; e < end; e += 4) {
        int pkt = packed[e];                 // 16 lanes/group share address
        int src = pkt & 0xFFFF;
        int cat = pkt >> 16;
        uint4 kv4 = *(const uint4*)(kv32 + ((size_t)src << 6) + (i16 << 2));
        float4 t4 = *(const float4*)(tel + (cat << 6) + (i16 << 2));
        // key = k + te; partial dot with q (4 channels/lane)
        float p;
        p = (__uint_as_float(kv4.x & 0xFFFF0000u) + t4.x) * q4.x;
        p = fmaf(__uint_as_float(kv4.y & 0xFFFF0000u) + t4.y, q4.y, p);
        p = fmaf(__uint_as_float(kv4.z & 0xFFFF0000u) + t4.z, q4.z, p);
        p = fmaf(__uint_as_float(kv4.w & 0xFFFF0000u) + t4.w, q4.w, p);
        // reduce across the 16-lane group
        p += __shfl_xor(p, 1); p += __shfl_xor(p, 2);
        p += __shfl_xor(p, 4); p += __shfl_xor(p, 8);
        float a = p * SCALE;
        float mn = fmaxf(m, a);
        float corr = __expf(m - mn);        // m=-1e30 first time -> underflows to 0
        float w = __expf(a - mn);
        float4 v4;
        v4.x = __uint_as_float(kv4.x << 16) + t4.x;
        v4.y = __uint_as_float(kv4.y << 16) + t4.y;
        v4.z = __uint_as_float(kv4.z << 16) + t4.z;
        v4.w = __uint_as_float(kv4.w << 16) + t4.w;
        acc.x = fmaf(w, v4.x, acc.x * corr);
        acc.y = fmaf(w, v4.y, acc.y * corr);
        acc.z = fmaf(w, v4.z, acc.z * corr);
        acc.w = fmaf(w, v4.w, acc.w * corr);
        l = fmaf(l, corr, w);
        m = mn;
    }
    // merge the 4 groups (flash-attention style)
    float M = fmaxf(m, __shfl_xor(m, 16));
    M = fmaxf(M, __shfl_xor(M, 32));
    float sc = __expf(m - M);
    l *= sc;
    acc.x *= sc; acc.y *= sc; acc.z *= sc; acc.w *= sc;
    l += __shfl_xor(l, 16); l += __shfl_xor(l, 32);
    acc.x += __shfl_xor(acc.x, 16); acc.x += __shfl_xor(acc.x, 32);
    acc.y += __shfl_xor(acc.y, 16); acc.y += __shfl_xor(acc.y, 32);
    acc.z += __shfl_xor(acc.z, 16); acc.z += __shfl_xor(acc.z, 32);
    acc.w += __shfl_xor(acc.w, 16); acc.w += __shfl_xor(acc.w, 32);
    float inv = (l > 0.f) ? 1.f / l : 0.f;
    float4 s4 = *(const float4*)(qs + (size_t)dst * 128 + 64 + (i16 << 2));
    float4 hv;
    hv.x = fmaxf(acc.x * inv + s4.x, 0.f);
    hv.y = fmaxf(acc.y * inv + s4.y, 0.f);
    hv.z = fmaxf(acc.z * inv + s4.z, 0.f);
    hv.w = fmaxf(acc.w * inv + s4.w, 0.f);
    if (g == 0) *(float4*)(h + (size_t)dst * H + (i16 << 2)) = hv;
    if (gW) {   // fused readout gate (final layer only)
        float4 g4 = *(const float4*)(gW + (i16 << 2));
        float p = hv.x * g4.x + hv.y * g4.y + hv.z * g4.z + hv.w * g4.w;
        p += __shfl_xor(p, 1); p += __shfl_xor(p, 2);
        p += __shfl_xor(p, 4); p += __shfl_xor(p, 8);
        if (lane == 0) gate[dst] = p + gb[0];
    }
}

// ---------------- fused per-graph readout ----------------
__global__ __launch_bounds__(256) void k_readout2(
    const float* __restrict__ h, const float* __restrict__ oW,
    const float* __restrict__ ob, const float* __restrict__ gate,
    const int* __restrict__ gs, float* __restrict__ out)
{
    __shared__ float wls[H * OUTD];
    __shared__ float hs[8][H + 1];
    __shared__ float red[256];
    __shared__ float den_s[8];
    __shared__ float gmax_s, den_tot;
    int t = threadIdx.x;
    int g = blockIdx.x;
    for (int i = t; i < H * OUTD; i += 256) wls[i] = oW[i];
    int beg = gs[g], end = gs[g + 1];
    float mx = -INFINITY;
    for (int n = beg + t; n < end; n += 256) mx = fmaxf(mx, gate[n]);
    red[t] = mx;
    __syncthreads();
    for (int sft = 128; sft > 0; sft >>= 1) {
        if (t < sft) red[t] = fmaxf(red[t], red[t + sft]);
        __syncthreads();
    }
    if (t == 0) gmax_s = red[0];
    __syncthreads();
    float gm = gmax_s;
    int ln = t >> 5, o = t & 31;
    float acc = 0.f, den = 0.f;
    for (int n0 = beg; n0 < end; n0 += 8) {
        __syncthreads();
        for (int i = t; i < 8 * H; i += 256) {
            int r = i >> 6, c = i & 63;
            int n = n0 + r;
            hs[r][c] = (n < end) ? h[(size_t)n * H + c] : 0.f;
        }
        __syncthreads();
        int n = n0 + ln;
        if (n < end) {
            float wt = __expf(gate[n] - gm);
            float d0 = 0.f;
            #pragma unroll
            for (int i = 0; i < H; i++) d0 += hs[ln][i] * wls[i * OUTD + o];
            acc += wt * d0;
            if (o == 0) den += wt;
        }
    }
    __syncthreads();
    red[t] = acc;
    if (o == 0) den_s[ln] = den;
    __syncthreads();
    for (int sft = 4; sft >= 1; sft >>= 1) {
        if (ln < sft) red[t] += red[t + sft * 32];
        __syncthreads();
    }
    if (t == 0) {
        float dt = 0.f;
        #pragma unroll
        for (int i = 0; i < 8; i++) dt += den_s[i];
        den_tot = dt;
    }
    __syncthreads();
    if (ln == 0) {
        float dt = den_tot;
        out[g * OUTD + o] = (dt > 0.f) ? red[o] / dt + ob[o] : 0.f;
    }
}

extern "C" void kernel_launch(void* const* d_in, const int* in_sizes, int n_in,
                              void* d_out, int out_size, void* d_ws, size_t ws_size,
                              hipStream_t stream)
{
    const int* x        = (const int*)d_in[0];
    const int* ei       = (const int*)d_in[1];
    const int* ea       = (const int*)d_in[2];
    const int* batch    = (const int*)d_in[3];
    const float* node_emb = (const float*)d_in[4];
    const float* edge_emb = (const float*)d_in[5];
    const float* Wq    = (const float*)d_in[6];
    const float* Wk    = (const float*)d_in[7];
    const float* Wv    = (const float*)d_in[8];
    const float* We    = (const float*)d_in[9];
    const float* Wskip = (const float*)d_in[10];
    const float* bq    = (const float*)d_in[11];
    const float* bk    = (const float*)d_in[12];
    const float* bv    = (const float*)d_in[13];
    const float* bskip = (const float*)d_in[14];
    const float* gate_W = (const float*)d_in[15];
    const float* gate_b = (const float*)d_in[16];
    const float* out_W  = (const float*)d_in[17];
    const float* out_b  = (const float*)d_in[18];
    float* out = (float*)d_out;

    const size_t NH = (size_t)N_NODES * H;
    float* ws   = (float*)d_ws;
    float* h    = ws;
    float* qs   = h + NH;                    // fp32 [q(64)|s(64)] per node
    unsigned* kv32 = (unsigned*)(qs + 2 * NH); // packed bf16 k|v, 64 uints/node
    float* te   = (float*)(kv32 + NH);
    float* gate = te + LAYERS * 10 * H;
    int* deg       = (int*)(gate + N_NODES);
    int* row_start = deg + N_NODES;
    int* cursor    = row_start + N_NODES;
    int* packed    = cursor + N_NODES;
    int* gs        = packed + N_EDGES;   // 257 ints
    int* bsum      = gs + NGRAPH + 1;    // 196

    hipMemsetAsync(deg, 0, N_NODES * sizeof(int), stream);

    k_front<<<NB_FRONT, 256, 0, stream>>>(x, node_emb, h, edge_emb, We, te, ei, deg, batch, gs);
    k_scan1<<<SCAN_NB, 256, 0, stream>>>(deg, bsum);
    k_scan23<<<SCAN_NB, 256, 0, stream>>>(deg, bsum, row_start, cursor);

    // layer 0: gemm fused with scatter (independent work, co-scheduled)
    k_gemm_scatter<<<NB_GEMM + NB_HIST, 256, 0, stream>>>(
        h, Wq, Wk, Wv, Wskip, bq, bk, bv, bskip, qs, kv32, ei, ea, cursor, packed);
    k_agg<<<(N_NODES + 3) / 4, 256, 0, stream>>>(
        row_start, cursor, packed, qs, kv32, te, h, nullptr, nullptr, nullptr);

    for (int l = 1; l < LAYERS; l++) {
        k_gemm<<<NB_GEMM, 256, 0, stream>>>(
            h,
            Wq + (size_t)l * H * H, Wk + (size_t)l * H * H,
            Wv + (size_t)l * H * H, Wskip + (size_t)l * H * H,
            bq + (size_t)l * H, bk + (size_t)l * H, bv + (size_t)l * H, bskip + (size_t)l * H,
            qs, kv32);
        const float* gw = (l == LAYERS - 1) ? gate_W : nullptr;
        const float* gb = (l == LAYERS - 1) ? gate_b : nullptr;
        float* gp       = (l == LAYERS - 1) ? gate : nullptr;
        k_agg<<<(N_NODES + 3) / 4, 256, 0, stream>>>(
            row_start, cursor, packed, qs, kv32, te + (size_t)l * 10 * H, h, gw, gb, gp);
    }

    k_readout2<<<NGRAPH, 256, 0, stream>>>(h, out_W, out_b, gate, gs, out);
}

// Round 14
// 483.051 us; speedup vs baseline: 18.6888x; 1.0092x over previous
//
#include <hip/hip_runtime.h>
#include <hip/hip_bf16.h>

#define N_NODES 50000
#define N_EDGES 800000
#define H 64
#define ED 32
#define LAYERS 3
#define NGRAPH 256
#define OUTD 32
#define SCALE 0.125f
#define SCAN_NB ((N_NODES + 255) / 256)   // 196

// fused front-end block ranges
#define NB_INIT 12500
#define NB_TE   8
#define NB_HIST 3125
#define NB_GB   2
#define NB_FRONT (NB_INIT + NB_TE + NB_HIST + NB_GB)
#define NB_GEMM ((N_NODES + 63) / 64)     // 782

typedef __attribute__((ext_vector_type(16))) float f16v;
typedef unsigned short ushort_t;

// fp32 -> bf16 round-to-nearest-even
__device__ __forceinline__ ushort_t f2bf(float f) {
    unsigned u = __float_as_uint(f);
    return (ushort_t)((u + 0x7FFFu + ((u >> 16) & 1u)) >> 16);
}

// ---------------- fused front end: init_h | te | hist | gbounds ----------------
__global__ __launch_bounds__(256) void k_front(
    const int* __restrict__ x, const float* __restrict__ node_emb, float* __restrict__ h,
    const float* __restrict__ edge_emb, const float* __restrict__ We, float* __restrict__ te,
    const int* __restrict__ ei, int* __restrict__ deg,
    const int* __restrict__ batch, int* __restrict__ gs)
{
    int b = blockIdx.x, t = threadIdx.x;
    if (b < NB_INIT) {
        int i = b * 256 + t;
        int n = i >> 6, c = i & 63;
        h[i] = node_emb[x[n] * H + c];
    } else if (b < NB_INIT + NB_TE) {
        int i = (b - NB_INIT) * 256 + t;
        if (i < LAYERS * 10 * H) {
            int c = i & 63;
            int cat = (i >> 6) % 10;
            int l = i / (10 * H);
            float acc = 0.f;
            for (int d = 0; d < ED; d++)
                acc += edge_emb[cat * ED + d] * We[((size_t)l * ED + d) * H + c];
            te[i] = acc;
        }
    } else if (b < NB_INIT + NB_TE + NB_HIST) {
        int e = (b - NB_INIT - NB_TE) * 256 + t;
        atomicAdd(&deg[ei[N_EDGES + e]], 1);
    } else {
        int g = (b - NB_INIT - NB_TE - NB_HIST) * 256 + t;
        if (g <= NGRAPH) {
            int lo = 0, hi = N_NODES;
            while (lo < hi) {
                int mid = (lo + hi) >> 1;
                if (batch[mid] < g) lo = mid + 1; else hi = mid;
            }
            gs[g] = lo;
        }
    }
}

// ---------------- scans ----------------
__global__ __launch_bounds__(256) void k_scan1(const int* __restrict__ deg, int* __restrict__ bsum) {
    __shared__ int red[256];
    int t = threadIdx.x;
    int i = blockIdx.x * 256 + t;
    red[t] = (i < N_NODES) ? deg[i] : 0;
    __syncthreads();
    for (int s = 128; s > 0; s >>= 1) {
        if (t < s) red[t] += red[t + s];
        __syncthreads();
    }
    if (t == 0) bsum[blockIdx.x] = red[0];
}

// merged scan2+scan3: each block redundantly scans the 196 block sums, then local scan
__global__ __launch_bounds__(256) void k_scan23(const int* __restrict__ deg, const int* __restrict__ bsum,
                                                int* __restrict__ row_start, int* __restrict__ cursor) {
    __shared__ int part[256];
    int t = threadIdx.x;
    part[t] = (t < SCAN_NB) ? bsum[t] : 0;
    __syncthreads();
    for (int off = 1; off < 256; off <<= 1) {
        int add = (t >= off) ? part[t - off] : 0;
        __syncthreads();
        part[t] += add;
        __syncthreads();
    }
    int boff = (blockIdx.x == 0) ? 0 : part[blockIdx.x - 1];
    __syncthreads();
    int i = blockIdx.x * 256 + t;
    int v = (i < N_NODES) ? deg[i] : 0;
    part[t] = v;
    __syncthreads();
    for (int off = 1; off < 256; off <<= 1) {
        int add = (t >= off) ? part[t - off] : 0;
        __syncthreads();
        part[t] += add;
        __syncthreads();
    }
    if (i < N_NODES) {
        int excl = part[t] - v + boff;
        row_start[i] = excl;
        cursor[i] = excl;
    }
}

// ---------------- gemm body: wave = matrix, lane = col ----------------
__device__ __forceinline__ void gemm_body(
    int bid, const float* __restrict__ h,
    const float* __restrict__ Wq, const float* __restrict__ Wk,
    const float* __restrict__ Wv, const float* __restrict__ Wsk,
    const float* __restrict__ bq, const float* __restrict__ bk,
    const float* __restrict__ bv, const float* __restrict__ bsk,
    float* __restrict__ qs, unsigned* __restrict__ kv32)
{
    int wvi = threadIdx.x >> 6, lane = threadIdx.x & 63;
    const float* Wm = (wvi == 0) ? Wq : (wvi == 1) ? Wk : (wvi == 2) ? Wv : Wsk;
    const float* bm = (wvi == 0) ? bq : (wvi == 1) ? bk : (wvi == 2) ? bv : bsk;
    f16v w0, w1, w2, w3;
    #pragma unroll
    for (int i = 0; i < 16; i++) w0[i] = Wm[i * H + lane];
    #pragma unroll
    for (int i = 0; i < 16; i++) w1[i] = Wm[(16 + i) * H + lane];
    #pragma unroll
    for (int i = 0; i < 16; i++) w2[i] = Wm[(32 + i) * H + lane];
    #pragma unroll
    for (int i = 0; i < 16; i++) w3[i] = Wm[(48 + i) * H + lane];
    float bias = bm[lane];
    int base = bid * 64;
    int nEnd = min(base + 64, N_NODES);
    for (int n = base; n < nEnd; n++) {
        const float* hrow = h + (size_t)n * H;
        f16v h0, h1, h2, h3;
        asm volatile(
            "s_load_dwordx16 %0, %4, 0x0\n\t"
            "s_load_dwordx16 %1, %4, 0x40\n\t"
            "s_load_dwordx16 %2, %4, 0x80\n\t"
            "s_load_dwordx16 %3, %4, 0xc0\n\t"
            "s_waitcnt lgkmcnt(0)"
            : "=s"(h0), "=s"(h1), "=s"(h2), "=s"(h3)
            : "s"(hrow));
        float acc = bias;
        #pragma unroll
        for (int i = 0; i < 16; i++) acc = fmaf(h0[i], w0[i], acc);
        #pragma unroll
        for (int i = 0; i < 16; i++) acc = fmaf(h1[i], w1[i], acc);
        #pragma unroll
        for (int i = 0; i < 16; i++) acc = fmaf(h2[i], w2[i], acc);
        #pragma unroll
        for (int i = 0; i < 16; i++) acc = fmaf(h3[i], w3[i], acc);
        if (wvi == 0)      qs[(size_t)n * 128 + lane] = acc;
        else if (wvi == 3) qs[(size_t)n * 128 + 64 + lane] = acc;
        else if (wvi == 1) ((ushort_t*)kv32)[(((size_t)n << 6) + lane) * 2 + 1] = f2bf(acc);
        else               ((ushort_t*)kv32)[(((size_t)n << 6) + lane) * 2 + 0] = f2bf(acc);
    }
}

// layers 1,2: plain gemm
__global__ __launch_bounds__(256, 1) void k_gemm(
    const float* __restrict__ h,
    const float* __restrict__ Wq, const float* __restrict__ Wk,
    const float* __restrict__ Wv, const float* __restrict__ Wsk,
    const float* __restrict__ bq, const float* __restrict__ bk,
    const float* __restrict__ bv, const float* __restrict__ bsk,
    float* __restrict__ qs, unsigned* __restrict__ kv32)
{
    gemm_body(blockIdx.x, h, Wq, Wk, Wv, Wsk, bq, bk, bv, bsk, qs, kv32);
}

// layer 0: gemm blocks [0,NB_GEMM), scatter blocks [NB_GEMM, NB_GEMM+NB_HIST)
__global__ __launch_bounds__(256, 1) void k_gemm_scatter(
    const float* __restrict__ h,
    const float* __restrict__ Wq, const float* __restrict__ Wk,
    const float* __restrict__ Wv, const float* __restrict__ Wsk,
    const float* __restrict__ bq, const float* __restrict__ bk,
    const float* __restrict__ bv, const float* __restrict__ bsk,
    float* __restrict__ qs, unsigned* __restrict__ kv32,
    const int* __restrict__ ei, const int* __restrict__ ea,
    int* __restrict__ cursor, int* __restrict__ packed)
{
    int b = blockIdx.x;
    if (b < NB_GEMM) {
        gemm_body(b, h, Wq, Wk, Wv, Wsk, bq, bk, bv, bsk, qs, kv32);
    } else {
        int e = (b - NB_GEMM) * 256 + threadIdx.x;
        int src = ei[e], dst = ei[N_EDGES + e], cat = ea[e];
        int pos = atomicAdd(&cursor[dst], 1);
        packed[pos] = src | (cat << 16);
    }
}

// per-edge load bundle
struct EdgeLd { uint4 kv; float4 t; };
__device__ __forceinline__ EdgeLd edge_load(int pkt, const unsigned* __restrict__ kv32,
                                            const float* tel, int i16) {
    EdgeLd r;
    r.kv = *(const uint4*)(kv32 + ((size_t)(pkt & 0xFFFF) << 6) + (i16 << 2));
    r.t  = *(const float4*)(tel + ((pkt >> 16) << 6) + (i16 << 2));
    return r;
}
__device__ __forceinline__ float edge_dot(const EdgeLd& e, const float4& q4) {
    float p;
    p = (__uint_as_float(e.kv.x & 0xFFFF0000u) + e.t.x) * q4.x;
    p = fmaf(__uint_as_float(e.kv.y & 0xFFFF0000u) + e.t.y, q4.y, p);
    p = fmaf(__uint_as_float(e.kv.z & 0xFFFF0000u) + e.t.z, q4.z, p);
    p = fmaf(__uint_as_float(e.kv.w & 0xFFFF0000u) + e.t.w, q4.w, p);
    p += __shfl_xor(p, 1); p += __shfl_xor(p, 2);
    p += __shfl_xor(p, 4); p += __shfl_xor(p, 8);
    return p * SCALE;
}
__device__ __forceinline__ float4 edge_val(const EdgeLd& e) {
    float4 v;
    v.x = __uint_as_float(e.kv.x << 16) + e.t.x;
    v.y = __uint_as_float(e.kv.y << 16) + e.t.y;
    v.z = __uint_as_float(e.kv.z << 16) + e.t.z;
    v.w = __uint_as_float(e.kv.w << 16) + e.t.w;
    return v;
}

// ---------------- fused gather v3: 4x16 lane-split + 4-deep MLP unroll ----------------
__global__ __launch_bounds__(256) void k_agg(
    const int* __restrict__ row_start, const int* __restrict__ row_end,
    const int* __restrict__ packed,
    const float* __restrict__ qs, const unsigned* __restrict__ kv32,
    const float* __restrict__ te, float* __restrict__ h,
    const float* __restrict__ gW, const float* __restrict__ gb, float* __restrict__ gate)
{
    __shared__ float tel[10 * 64];
    for (int i = threadIdx.x; i < 10 * 64; i += 256) tel[i] = te[i];
    __syncthreads();
    int wave = threadIdx.x >> 6, lane = threadIdx.x & 63;
    int g = lane >> 4, i16 = lane & 15;
    int dst = blockIdx.x * 4 + wave;
    if (dst >= N_NODES) return;
    int beg = row_start[dst], end = row_end[dst];
    float4 q4 = *(const float4*)(qs + (size_t)dst * 128 + (i16 << 2));
    float m = -1e30f, l = 0.f;
    float4 acc = {0.f, 0.f, 0.f, 0.f};
    int e = beg + g;
    // main loop: 4 edges per group in flight (stride 4 within group)
    for (; e + 12 < end; e += 16) {
        int p0 = packed[e], p1 = packed[e + 4], p2 = packed[e + 8], p3 = packed[e + 12];
        EdgeLd e0 = edge_load(p0, kv32, tel, i16);
        EdgeLd e1 = edge_load(p1, kv32, tel, i16);
        EdgeLd e2 = edge_load(p2, kv32, tel, i16);
        EdgeLd e3 = edge_load(p3, kv32, tel, i16);
        float a0 = edge_dot(e0, q4), a1 = edge_dot(e1, q4);
        float a2 = edge_dot(e2, q4), a3 = edge_dot(e3, q4);
        float mn = fmaxf(m, fmaxf(fmaxf(a0, a1), fmaxf(a2, a3)));
        float corr = __expf(m - mn);
        float w0 = __expf(a0 - mn), w1 = __expf(a1 - mn);
        float w2 = __expf(a2 - mn), w3 = __expf(a3 - mn);
        float4 v0 = edge_val(e0), v1 = edge_val(e1), v2 = edge_val(e2), v3 = edge_val(e3);
        acc.x = fmaf(w0, v0.x, fmaf(w1, v1.x, fmaf(w2, v2.x, fmaf(w3, v3.x, acc.x * corr))));
        acc.y = fmaf(w0, v0.y, fmaf(w1, v1.y, fmaf(w2, v2.y, fmaf(w3, v3.y, acc.y * corr))));
        acc.z = fmaf(w0, v0.z, fmaf(w1, v1.z, fmaf(w2, v2.z, fmaf(w3, v3.z, acc.z * corr))));
        acc.w = fmaf(w0, v0.w, fmaf(w1, v1.w, fmaf(w2, v2.w, fmaf(w3, v3.w, acc.w * corr))));
        l = fmaf(l, corr, (w0 + w1) + (w2 + w3));
        m = mn;
    }
    // remainder: one edge at a time
    for (; e < end; e += 4) {
        int pkt = packed[e];
        EdgeLd e0 = edge_load(pkt, kv32, tel, i16);
        float a = edge_dot(e0, q4);
        float mn = fmaxf(m, a);
        float corr = __expf(m - mn);
        float w = __expf(a - mn);
        float4 v4 = edge_val(e0);
        acc.x = fmaf(w, v4.x, acc.x * corr);
        acc.y = fmaf(w, v4.y, acc.y * corr);
        acc.z = fmaf(w, v4.z, acc.z * corr);
        acc.w = fmaf(w, v4.w, acc.w * corr);
        l = fmaf(l, corr, w);
        m = mn;
    }
    // merge the 4 groups (flash-attention style)
    float M = fmaxf(m, __shfl_xor(m, 16));
    M = fmaxf(M, __shfl_xor(M, 32));
    float sc = __expf(m - M);
    l *= sc;
    acc.x *= sc; acc.y *= sc; acc.z *= sc; acc.w *= sc;
    l += __shfl_xor(l, 16); l += __shfl_xor(l, 32);
    acc.x += __shfl_xor(acc.x, 16); acc.x += __shfl_xor(acc.x, 32);
    acc.y += __shfl_xor(acc.y, 16); acc.y += __shfl_xor(acc.y, 32);
    acc.z += __shfl_xor(acc.z, 16); acc.z += __shfl_xor(acc.z, 32);
    acc.w += __shfl_xor(acc.w, 16); acc.w += __shfl_xor(acc.w, 32);
    float inv = (l > 0.f) ? 1.f / l : 0.f;
    float4 s4 = *(const float4*)(qs + (size_t)dst * 128 + 64 + (i16 << 2));
    float4 hv;
    hv.x = fmaxf(acc.x * inv + s4.x, 0.f);
    hv.y = fmaxf(acc.y * inv + s4.y, 0.f);
    hv.z = fmaxf(acc.z * inv + s4.z, 0.f);
    hv.w = fmaxf(acc.w * inv + s4.w, 0.f);
    if (g == 0) *(float4*)(h + (size_t)dst * H + (i16 << 2)) = hv;
    if (gW) {   // fused readout gate (final layer only)
        float4 g4 = *(const float4*)(gW + (i16 << 2));
        float p = hv.x * g4.x + hv.y * g4.y + hv.z * g4.z + hv.w * g4.w;
        p += __shfl_xor(p, 1); p += __shfl_xor(p, 2);
        p += __shfl_xor(p, 4); p += __shfl_xor(p, 8);
        if (lane == 0) gate[dst] = p + gb[0];
    }
}

// ---------------- fused per-graph readout ----------------
__global__ __launch_bounds__(256) void k_readout2(
    const float* __restrict__ h, const float* __restrict__ oW,
    const float* __restrict__ ob, const float* __restrict__ gate,
    const int* __restrict__ gs, float* __restrict__ out)
{
    __shared__ float wls[H * OUTD];
    __shared__ float hs[8][H + 1];
    __shared__ float red[256];
    __shared__ float den_s[8];
    __shared__ float gmax_s, den_tot;
    int t = threadIdx.x;
    int g = blockIdx.x;
    for (int i = t; i < H * OUTD; i += 256) wls[i] = oW[i];
    int beg = gs[g], end = gs[g + 1];
    float mx = -INFINITY;
    for (int n = beg + t; n < end; n += 256) mx = fmaxf(mx, gate[n]);
    red[t] = mx;
    __syncthreads();
    for (int sft = 128; sft > 0; sft >>= 1) {
        if (t < sft) red[t] = fmaxf(red[t], red[t + sft]);
        __syncthreads();
    }
    if (t == 0) gmax_s = red[0];
    __syncthreads();
    float gm = gmax_s;
    int ln = t >> 5, o = t & 31;
    float acc = 0.f, den = 0.f;
    for (int n0 = beg; n0 < end; n0 += 8) {
        __syncthreads();
        for (int i = t; i < 8 * H; i += 256) {
            int r = i >> 6, c = i & 63;
            int n = n0 + r;
            hs[r][c] = (n < end) ? h[(size_t)n * H + c] : 0.f;
        }
        __syncthreads();
        int n = n0 + ln;
        if (n < end) {
            float wt = __expf(gate[n] - gm);
            float d0 = 0.f;
            #pragma unroll
            for (int i = 0; i < H; i++) d0 += hs[ln][i] * wls[i * OUTD + o];
            acc += wt * d0;
            if (o == 0) den += wt;
        }
    }
    __syncthreads();
    red[t] = acc;
    if (o == 0) den_s[ln] = den;
    __syncthreads();
    for (int sft = 4; sft >= 1; sft >>= 1) {
        if (ln < sft) red[t] += red[t + sft * 32];
        __syncthreads();
    }
    if (t == 0) {
        float dt = 0.f;
        #pragma unroll
        for (int i = 0; i < 8; i++) dt += den_s[i];
        den_tot = dt;
    }
    __syncthreads();
    if (ln == 0) {
        float dt = den_tot;
        out[g * OUTD + o] = (dt > 0.f) ? red[o] / dt + ob[o] : 0.f;
    }
}

extern "C" void kernel_launch(void* const* d_in, const int* in_sizes, int n_in,
                              void* d_out, int out_size, void* d_ws, size_t ws_size,
                              hipStream_t stream)
{
    const int* x        = (const int*)d_in[0];
    const int* ei       = (const int*)d_in[1];
    const int* ea       = (const int*)d_in[2];
    const int* batch    = (const int*)d_in[3];
    const float* node_emb = (const float*)d_in[4];
    const float* edge_emb = (const float*)d_in[5];
    const float* Wq    = (const float*)d_in[6];
    const float* Wk    = (const float*)d_in[7];
    const float* Wv    = (const float*)d_in[8];
    const float* We    = (const float*)d_in[9];
    const float* Wskip = (const float*)d_in[10];
    const float* bq    = (const float*)d_in[11];
    const float* bk    = (const float*)d_in[12];
    const float* bv    = (const float*)d_in[13];
    const float* bskip = (const float*)d_in[14];
    const float* gate_W = (const float*)d_in[15];
    const float* gate_b = (const float*)d_in[16];
    const float* out_W  = (const float*)d_in[17];
    const float* out_b  = (const float*)d_in[18];
    float* out = (float*)d_out;

    const size_t NH = (size_t)N_NODES * H;
    float* ws   = (float*)d_ws;
    float* h    = ws;
    float* qs   = h + NH;                    // fp32 [q(64)|s(64)] per node
    unsigned* kv32 = (unsigned*)(qs + 2 * NH); // packed bf16 k|v, 64 uints/node
    float* te   = (float*)(kv32 + NH);
    float* gate = te + LAYERS * 10 * H;
    int* deg       = (int*)(gate + N_NODES);
    int* row_start = deg + N_NODES;
    int* cursor    = row_start + N_NODES;
    int* packed    = cursor + N_NODES;
    int* gs        = packed + N_EDGES;   // 257 ints
    int* bsum      = gs + NGRAPH + 1;    // 196

    hipMemsetAsync(deg, 0, N_NODES * sizeof(int), stream);

    k_front<<<NB_FRONT, 256, 0, stream>>>(x, node_emb, h, edge_emb, We, te, ei, deg, batch, gs);
    k_scan1<<<SCAN_NB, 256, 0, stream>>>(deg, bsum);
    k_scan23<<<SCAN_NB, 256, 0, stream>>>(deg, bsum, row_start, cursor);

    // layer 0: gemm fused with scatter (independent work, co-scheduled)
    k_gemm_scatter<<<NB_GEMM + NB_HIST, 256, 0, stream>>>(
        h, Wq, Wk, Wv, Wskip, bq, bk, bv, bskip, qs, kv32, ei, ea, cursor, packed);
    k_agg<<<(N_NODES + 3) / 4, 256, 0, stream>>>(
        row_start, cursor, packed, qs, kv32, te, h, nullptr, nullptr, nullptr);

    for (int l = 1; l < LAYERS; l++) {
        k_gemm<<<NB_GEMM, 256, 0, stream>>>(
            h,
            Wq + (size_t)l * H * H, Wk + (size_t)l * H * H,
            Wv + (size_t)l * H * H, Wskip + (size_t)l * H * H,
            bq + (size_t)l * H, bk + (size_t)l * H, bv + (size_t)l * H, bskip + (size_t)l * H,
            qs, kv32);
        const float* gw = (l == LAYERS - 1) ? gate_W : nullptr;
        const float* gb = (l == LAYERS - 1) ? gate_b : nullptr;
        float* gp       = (l == LAYERS - 1) ? gate : nullptr;
        k_agg<<<(N_NODES + 3) / 4, 256, 0, stream>>>(
            row_start, cursor, packed, qs, kv32, te + (size_t)l * 10 * H, h, gw, gb, gp);
    }

    k_readout2<<<NGRAPH, 256, 0, stream>>>(h, out_W, out_b, gate, gs, out);
}